// Round 7
// baseline (5083.187 us; speedup 1.0000x reference)
//
#include <hip/hip_runtime.h>
#include <math.h>

#define T_TOK 8192
#define H_DIM 2048
#define F_DIM 4096
#define E_NUM 8
#define MAXPAIR (T_TOK * 2)
#define MAX_MT 136
#define BM 128
#define BN 128
#define BK 32
#define NCONV 2048  // w2-convert blocks fused into gemm1 dispatch

typedef __attribute__((ext_vector_type(4))) float f32x4;
typedef __attribute__((ext_vector_type(8))) short s16x8;
typedef __attribute__((ext_vector_type(8))) __bf16 bf16x8;
typedef __attribute__((ext_vector_type(4))) unsigned short u16x4;

__device__ __forceinline__ unsigned short f2bf(float f) {
  unsigned int u = __float_as_uint(f);
  u += 0x7FFFu + ((u >> 16) & 1u);
  return (unsigned short)(u >> 16);
}

__device__ __forceinline__ s16x8 pack8(f32x4 a, f32x4 b) {
  s16x8 r;
  r[0] = (short)f2bf(a.x); r[1] = (short)f2bf(a.y);
  r[2] = (short)f2bf(a.z); r[3] = (short)f2bf(a.w);
  r[4] = (short)f2bf(b.x); r[5] = (short)f2bf(b.y);
  r[6] = (short)f2bf(b.z); r[7] = (short)f2bf(b.w);
  return r;
}

#define GLD16(gsrc, ldst)                                                      \
  __builtin_amdgcn_global_load_lds(                                            \
      (__attribute__((address_space(1))) void*)(gsrc),                         \
      (__attribute__((address_space(3))) void*)(ldst), 16, 0, 0)

// ---------------------------------------------------------------------------
// Router: logits (fp32, exact) + x->bf16 conversion + top2 + counts
// ---------------------------------------------------------------------------
__global__ __launch_bounds__(256) void router_kernel(
    const float* __restrict__ x, const float* __restrict__ gw,
    float* __restrict__ logits, unsigned short* __restrict__ xb,
    int* __restrict__ ctrl, int* __restrict__ tIdx, float* __restrict__ tW) {
  const int wid = threadIdx.x >> 6, lane = threadIdx.x & 63;
  const int t = blockIdx.x * 4 + wid;
  const float* xr = x + (size_t)t * H_DIM;
  float acc[E_NUM];
#pragma unroll
  for (int e = 0; e < E_NUM; ++e) acc[e] = 0.f;
#pragma unroll
  for (int c = 0; c < H_DIM / 256; ++c) {
    const int h0 = c * 256 + lane * 4;
    f32x4 xv = *(const f32x4*)(xr + h0);
    u16x4 p;
    p.x = f2bf(xv.x); p.y = f2bf(xv.y); p.z = f2bf(xv.z); p.w = f2bf(xv.w);
    *(u16x4*)(xb + (size_t)t * H_DIM + h0) = p;
#pragma unroll
    for (int e = 0; e < E_NUM; ++e) {
      f32x4 gv = *(const f32x4*)(gw + (size_t)e * H_DIM + h0);
      acc[e] += xv.x * gv.x + xv.y * gv.y + xv.z * gv.z + xv.w * gv.w;
    }
  }
#pragma unroll
  for (int e = 0; e < E_NUM; ++e) {
#pragma unroll
    for (int off = 32; off >= 1; off >>= 1) acc[e] += __shfl_xor(acc[e], off, 64);
  }
  if (lane == 0) {
#pragma unroll
    for (int e = 0; e < E_NUM; ++e) logits[(size_t)t * E_NUM + e] = acc[e];
    int i0 = 0;
    float m0 = acc[0];
    for (int e = 1; e < E_NUM; ++e)
      if (acc[e] > m0) { m0 = acc[e]; i0 = e; }
    int i1 = -1;
    float m1 = -3.4e38f;
    for (int e = 0; e < E_NUM; ++e)
      if (e != i0 && acc[e] > m1) { m1 = acc[e]; i1 = e; }
    float ex = expf(m1 - m0);
    float w0 = 1.f / (1.f + ex);
    float w1 = ex * w0;
    tIdx[t * 2] = i0; tIdx[t * 2 + 1] = i1;
    tW[t * 2] = w0;  tW[t * 2 + 1] = w1;
    atomicAdd(&ctrl[i0], 1);
    atomicAdd(&ctrl[i1], 1);
  }
}

// ---------------------------------------------------------------------------
// Plan (parallel): offsets, cursors, flat M-tile map
// ctrl: [0..7] counts, [8..15] offsets, [16..23] cursors, [24] mtTotal,
//       [32..) tileExpert, [32+MAX_MT..) tileMBase, [512..768) panel flags
// ---------------------------------------------------------------------------
__global__ __launch_bounds__(256) void plan_kernel(int* __restrict__ ctrl) {
  __shared__ int cnt[E_NUM], offs[E_NUM + 1], tbase[E_NUM + 1];
  const int t = threadIdx.x;
  if (t < E_NUM) cnt[t] = ctrl[t];
  __syncthreads();
  if (t == 0) {
    int off = 0, mt = 0;
    for (int e = 0; e < E_NUM; ++e) {
      offs[e] = off; tbase[e] = mt;
      ctrl[8 + e] = off;
      ctrl[16 + e] = off;
      off += cnt[e];
      mt += (cnt[e] + BM - 1) / BM;
    }
    offs[E_NUM] = off; tbase[E_NUM] = mt;
    ctrl[24] = mt;
  }
  __syncthreads();
  const int total = tbase[E_NUM];
  for (int i = t; i < total; i += 256) {
    int e = 0;
    while (tbase[e + 1] <= i) ++e;
    ctrl[32 + i] = e;
    ctrl[32 + MAX_MT + i] = offs[e] + (i - tbase[e]) * BM;
  }
}

__global__ __launch_bounds__(256) void scatter_kernel(
    const int* __restrict__ tIdx, const float* __restrict__ tW,
    int* __restrict__ ctrl, int* __restrict__ pairTok,
    float* __restrict__ pairWgt) {
  const int t = blockIdx.x * 256 + threadIdx.x;
  if (t >= T_TOK) return;
#pragma unroll
  for (int j = 0; j < 2; ++j) {
    const int e = tIdx[t * 2 + j];
    const int pos = atomicAdd(&ctrl[16 + e], 1);
    pairTok[pos] = t;
    pairWgt[pos] = tW[t * 2 + j];
  }
}

// ---------------------------------------------------------------------------
// GEMM1: h = silu(x·w1^T) * (x·w3^T)  (bf16 out)
// Round-5 verified pipeline: 3 LDS buffers, depth-2 counted vmcnt(12),
// raw barriers, setprio. B from bf16 panels via global_load_lds.
// NEW: w1/w3 panels converted fp32->bf16 by FIRST-TOUCHER gemm blocks
// (per-(e,nt) flag, CAS claim, threadfence release / acquire spin) —
// removes the 2 serial convert dispatches; traffic hides under compute.
// w2-convert blocks stay fused 1-per-3 (round-5 verified).
// ---------------------------------------------------------------------------
template <int BBF>
__global__ __launch_bounds__(256, 2) void gemm1_kernel(
    const float* __restrict__ w1f, const float* __restrict__ w3f,
    unsigned short* __restrict__ w1b, unsigned short* __restrict__ w3b,
    const unsigned short* __restrict__ xb, const int* __restrict__ ctrl,
    int* __restrict__ flags, const int* __restrict__ pairTok,
    unsigned short* __restrict__ hbuf, const float* __restrict__ w2f,
    unsigned short* __restrict__ w2b, int nconv) {
  // ---- demux: interleaved w2-convert blocks (block-uniform, no barriers)
  int gid = blockIdx.x;
  const int nconv3 = nconv * 3;
  if (gid < nconv3) {
    if ((gid % 3) == 2) {
      const int cid = gid / 3;
      const long long per = (long long)E_NUM * F_DIM * H_DIM / 8 / NCONV;
      long long i = (long long)cid * per + threadIdx.x;
      const long long end = (long long)(cid + 1) * per;
      for (; i < end; i += 256) {
        f32x4 a = *(const f32x4*)(w2f + i * 8);
        f32x4 b = *(const f32x4*)(w2f + i * 8 + 4);
        *(s16x8*)(w2b + i * 8) = pack8(a, b);
      }
      return;
    }
    gid = gid - (gid + 1) / 3;
  } else {
    gid = gid - nconv;
  }

  const int mtTotal = ctrl[24];
  const int mt = gid >> 5;   // nt-major: same-weight-tile blocks 32 apart
  const int nt = gid & 31;   // -> same XCD -> L2 reuse
  if (mt >= mtTotal) return;
  const int e = ctrl[32 + mt];
  const int mbase = ctrl[32 + MAX_MT + mt];
  int mValid = ctrl[8 + e] + ctrl[e] - mbase;
  if (mValid > BM) mValid = BM;
  const int nbase = nt * BN;

  __shared__ __align__(16) short sA[3][BM * BK];
  __shared__ __align__(16) short sB1[3][BM * BK];
  __shared__ __align__(16) short sB3[3][BM * BK];
  __shared__ int sTok[BM];
  __shared__ int sClaim;

  const int tid = threadIdx.x;
  if (tid < BM) sTok[tid] = pairTok[mbase + (tid < mValid ? tid : 0)];

  const size_t wbase = (size_t)e * F_DIM * H_DIM;

  // ---- first-toucher panel conversion (BBF only) --------------------------
  if constexpr (BBF) {
    int* flag = flags + e * 32 + nt;
    if (tid == 0) {
      int cur = __hip_atomic_load(flag, __ATOMIC_ACQUIRE,
                                  __HIP_MEMORY_SCOPE_AGENT);
      int mine = 0;
      if (cur == 0) {
        int exp = 0;
        mine = __hip_atomic_compare_exchange_strong(
            flag, &exp, 1, __ATOMIC_ACQ_REL, __ATOMIC_ACQUIRE,
            __HIP_MEMORY_SCOPE_AGENT);
      }
      sClaim = mine;
    }
    __syncthreads();
    if (sClaim) {
      const size_t pb = wbase + (size_t)nbase * H_DIM;  // panel base (elems)
      const int NPE = BM * H_DIM / 8;                   // 32768 8-elem chunks
      for (int i = tid; i < NPE; i += 256) {
        f32x4 a = *(const f32x4*)(w1f + pb + (size_t)i * 8);
        f32x4 b = *(const f32x4*)(w1f + pb + (size_t)i * 8 + 4);
        *(s16x8*)(w1b + pb + (size_t)i * 8) = pack8(a, b);
        a = *(const f32x4*)(w3f + pb + (size_t)i * 8);
        b = *(const f32x4*)(w3f + pb + (size_t)i * 8 + 4);
        *(s16x8*)(w3b + pb + (size_t)i * 8) = pack8(a, b);
      }
      __syncthreads();
      if (tid == 0) {
        __threadfence();
        __hip_atomic_store(flag, 2, __ATOMIC_RELEASE,
                           __HIP_MEMORY_SCOPE_AGENT);
      }
    } else {
      if (tid == 0) {
        while (__hip_atomic_load(flag, __ATOMIC_ACQUIRE,
                                 __HIP_MEMORY_SCOPE_AGENT) != 2)
          __builtin_amdgcn_s_sleep(8);
      }
    }
  }
  __syncthreads();  // also covers sTok staging

  const int c0 = tid, c1 = tid + 256;
  const int r0 = c0 >> 2, r1 = c1 >> 2;
  const int kg0 = (c0 & 3) ^ ((r0 >> 1) & 3);
  const int kg1 = (c1 & 3) ^ ((r1 >> 1) & 3);

  const unsigned short* srcA0 = xb + (size_t)sTok[r0] * H_DIM + kg0 * 8;
  const unsigned short* srcA1 = xb + (size_t)sTok[r1] * H_DIM + kg1 * 8;
  const float *f10, *f11, *f30, *f31;
  const unsigned short *p10, *p11, *p30, *p31;
  if constexpr (BBF) {
    p10 = w1b + wbase + (size_t)(nbase + r0) * H_DIM + kg0 * 8;
    p11 = w1b + wbase + (size_t)(nbase + r1) * H_DIM + kg1 * 8;
    p30 = w3b + wbase + (size_t)(nbase + r0) * H_DIM + kg0 * 8;
    p31 = w3b + wbase + (size_t)(nbase + r1) * H_DIM + kg1 * 8;
  } else {
    f10 = w1f + wbase + (size_t)(nbase + r0) * H_DIM + kg0 * 8;
    f11 = w1f + wbase + (size_t)(nbase + r1) * H_DIM + kg1 * 8;
    f30 = w3f + wbase + (size_t)(nbase + r0) * H_DIM + kg0 * 8;
    f31 = w3f + wbase + (size_t)(nbase + r1) * H_DIM + kg1 * 8;
  }

  f32x4 acc1[4][4], acc3[4][4];
  const f32x4 fz = {0.f, 0.f, 0.f, 0.f};
#pragma unroll
  for (int i = 0; i < 4; ++i)
#pragma unroll
    for (int j = 0; j < 4; ++j) { acc1[i][j] = fz; acc3[i][j] = fz; }

  const int lane = tid & 63, wid = tid >> 6;
  const int wm = (wid >> 1) * 64, wn = (wid & 1) * 64;
  const int rl = lane & 15, kq = lane >> 4;

  int aIdx[4], bIdx[4];
#pragma unroll
  for (int i = 0; i < 4; ++i) {
    const int ra = wm + i * 16 + rl;
    aIdx[i] = ra * BK + ((kq ^ ((ra >> 1) & 3)) * 8);
    const int rb = wn + i * 16 + rl;
    bIdx[i] = rb * BK + ((kq ^ ((rb >> 1) & 3)) * 8);
  }

#define STAGE1(buf, k0)                                                        \
  {                                                                            \
    GLD16(srcA0 + (k0), &sA[buf][c0 * 8]);                                     \
    GLD16(srcA1 + (k0), &sA[buf][c1 * 8]);                                     \
    if constexpr (BBF) {                                                       \
      GLD16(p10 + (k0), &sB1[buf][c0 * 8]);                                    \
      GLD16(p11 + (k0), &sB1[buf][c1 * 8]);                                    \
      GLD16(p30 + (k0), &sB3[buf][c0 * 8]);                                    \
      GLD16(p31 + (k0), &sB3[buf][c1 * 8]);                                    \
    } else {                                                                   \
      f32x4 t0 = *(const f32x4*)(f10 + (k0));                                  \
      f32x4 t1 = *(const f32x4*)(f10 + (k0) + 4);                              \
      *(s16x8*)&sB1[buf][c0 * 8] = pack8(t0, t1);                              \
      t0 = *(const f32x4*)(f11 + (k0));                                        \
      t1 = *(const f32x4*)(f11 + (k0) + 4);                                    \
      *(s16x8*)&sB1[buf][c1 * 8] = pack8(t0, t1);                              \
      t0 = *(const f32x4*)(f30 + (k0));                                        \
      t1 = *(const f32x4*)(f30 + (k0) + 4);                                    \
      *(s16x8*)&sB3[buf][c0 * 8] = pack8(t0, t1);                              \
      t0 = *(const f32x4*)(f31 + (k0));                                        \
      t1 = *(const f32x4*)(f31 + (k0) + 4);                                    \
      *(s16x8*)&sB3[buf][c1 * 8] = pack8(t0, t1);                              \
    }                                                                          \
  }

  STAGE1(0, 0);
  STAGE1(1, BK);

  const int NS = H_DIM / BK;  // 64
  int cur = 0;
  for (int s = 0; s < NS; ++s) {
    if (s + 2 < NS) {
      const int nxt = (cur + 2 >= 3) ? cur - 1 : cur + 2;
      STAGE1(nxt, (s + 2) * BK);
      if constexpr (BBF)
        asm volatile("s_waitcnt vmcnt(12)" ::: "memory");
      else
        asm volatile("s_waitcnt vmcnt(0) lgkmcnt(0)" ::: "memory");
    } else if (s + 2 == NS) {
      if constexpr (BBF)
        asm volatile("s_waitcnt vmcnt(6)" ::: "memory");
      else
        asm volatile("s_waitcnt vmcnt(0) lgkmcnt(0)" ::: "memory");
    } else {
      asm volatile("s_waitcnt vmcnt(0) lgkmcnt(0)" ::: "memory");
    }
    __builtin_amdgcn_s_barrier();   // all waves' stage-s loads landed
    asm volatile("" ::: "memory");

    bf16x8 af[4], bf1[4], bf3[4];
#pragma unroll
    for (int i = 0; i < 4; ++i) {
      af[i] = *(const bf16x8*)&sA[cur][aIdx[i]];
      bf1[i] = *(const bf16x8*)&sB1[cur][bIdx[i]];
      bf3[i] = *(const bf16x8*)&sB3[cur][bIdx[i]];
    }
    __builtin_amdgcn_s_setprio(1);
#pragma unroll
    for (int mr = 0; mr < 4; ++mr)
#pragma unroll
      for (int nr = 0; nr < 4; ++nr) {
        acc1[mr][nr] = __builtin_amdgcn_mfma_f32_16x16x32_bf16(
            af[mr], bf1[nr], acc1[mr][nr], 0, 0, 0);
        acc3[mr][nr] = __builtin_amdgcn_mfma_f32_16x16x32_bf16(
            af[mr], bf3[nr], acc3[mr][nr], 0, 0, 0);
      }
    __builtin_amdgcn_s_setprio(0);
    asm volatile("" ::: "memory");
    __builtin_amdgcn_s_barrier();   // reads of buf `cur` done before overwrite
    cur = (cur + 1 >= 3) ? 0 : cur + 1;
  }

#pragma unroll
  for (int mr = 0; mr < 4; ++mr) {
#pragma unroll
    for (int j = 0; j < 4; ++j) {
      const int row = wm + mr * 16 + kq * 4 + j;
      if (row < mValid) {
        unsigned short* dst =
            hbuf + (size_t)(mbase + row) * F_DIM + nbase + wn + rl;
#pragma unroll
        for (int nr = 0; nr < 4; ++nr) {
          const float z = acc1[mr][nr][j];
          const float hv = (z / (1.f + expf(-z))) * acc3[mr][nr][j];
          dst[nr * 16] = f2bf(hv);
        }
      }
    }
  }
#undef STAGE1
}

// ---------------------------------------------------------------------------
// GEMM2: out[tok] += wgt * (h·w2^T)   (round-5 verified pipeline)
// ---------------------------------------------------------------------------
template <int BBF>
__global__ __launch_bounds__(256, 2) void gemm2_kernel(
    const float* __restrict__ w2f, const unsigned short* __restrict__ w2b,
    const unsigned short* __restrict__ hbuf, const int* __restrict__ ctrl,
    const int* __restrict__ pairTok, const float* __restrict__ pairWgt,
    float* __restrict__ out) {
  const int mtTotal = ctrl[24];
  const int mt = blockIdx.x >> 4;
  const int nt = blockIdx.x & 15;
  if (mt >= mtTotal) return;
  const int e = ctrl[32 + mt];
  const int mbase = ctrl[32 + MAX_MT + mt];
  int mValid = ctrl[8 + e] + ctrl[e] - mbase;
  if (mValid > BM) mValid = BM;
  const int nbase = nt * BN;

  __shared__ __align__(16) short sA[3][BM * BK];
  __shared__ __align__(16) short sB[3][BM * BK];
  __shared__ int sTok[BM];
  __shared__ float sWgt[BM];

  const int tid = threadIdx.x;
  if (tid < BM) {
    const int p = mbase + (tid < mValid ? tid : 0);
    sTok[tid] = pairTok[p];
    sWgt[tid] = pairWgt[p];
  }
  __syncthreads();

  const int c0 = tid, c1 = tid + 256;
  const int r0 = c0 >> 2, r1 = c1 >> 2;
  const int kg0 = (c0 & 3) ^ ((r0 >> 1) & 3);
  const int kg1 = (c1 & 3) ^ ((r1 >> 1) & 3);

  size_t pa0 = (size_t)(mbase + r0); if (pa0 > MAXPAIR - 1) pa0 = MAXPAIR - 1;
  size_t pa1 = (size_t)(mbase + r1); if (pa1 > MAXPAIR - 1) pa1 = MAXPAIR - 1;
  const unsigned short* srcA0 = hbuf + pa0 * F_DIM + kg0 * 8;
  const unsigned short* srcA1 = hbuf + pa1 * F_DIM + kg1 * 8;
  const size_t wbase = (size_t)e * H_DIM * F_DIM;
  const float *fw0, *fw1;
  const unsigned short *pw0, *pw1;
  if constexpr (BBF) {
    pw0 = w2b + wbase + (size_t)(nbase + r0) * F_DIM + kg0 * 8;
    pw1 = w2b + wbase + (size_t)(nbase + r1) * F_DIM + kg1 * 8;
  } else {
    fw0 = w2f + wbase + (size_t)(nbase + r0) * F_DIM + kg0 * 8;
    fw1 = w2f + wbase + (size_t)(nbase + r1) * F_DIM + kg1 * 8;
  }

  f32x4 acc[4][4];
  const f32x4 fz = {0.f, 0.f, 0.f, 0.f};
#pragma unroll
  for (int i = 0; i < 4; ++i)
#pragma unroll
    for (int j = 0; j < 4; ++j) acc[i][j] = fz;

  const int lane = tid & 63, wid = tid >> 6;
  const int wm = (wid >> 1) * 64, wn = (wid & 1) * 64;
  const int rl = lane & 15, kq = lane >> 4;

  int aIdx[4], bIdx[4];
#pragma unroll
  for (int i = 0; i < 4; ++i) {
    const int ra = wm + i * 16 + rl;
    aIdx[i] = ra * BK + ((kq ^ ((ra >> 1) & 3)) * 8);
    const int rb = wn + i * 16 + rl;
    bIdx[i] = rb * BK + ((kq ^ ((rb >> 1) & 3)) * 8);
  }

#define STAGE2(buf, k0)                                                        \
  {                                                                            \
    GLD16(srcA0 + (k0), &sA[buf][c0 * 8]);                                     \
    GLD16(srcA1 + (k0), &sA[buf][c1 * 8]);                                     \
    if constexpr (BBF) {                                                       \
      GLD16(pw0 + (k0), &sB[buf][c0 * 8]);                                     \
      GLD16(pw1 + (k0), &sB[buf][c1 * 8]);                                     \
    } else {                                                                   \
      f32x4 t0 = *(const f32x4*)(fw0 + (k0));                                  \
      f32x4 t1 = *(const f32x4*)(fw0 + (k0) + 4);                              \
      *(s16x8*)&sB[buf][c0 * 8] = pack8(t0, t1);                               \
      t0 = *(const f32x4*)(fw1 + (k0));                                        \
      t1 = *(const f32x4*)(fw1 + (k0) + 4);                                    \
      *(s16x8*)&sB[buf][c1 * 8] = pack8(t0, t1);                               \
    }                                                                          \
  }

  STAGE2(0, 0);
  STAGE2(1, BK);

  const int NS = F_DIM / BK;  // 128
  int cur = 0;
  for (int s = 0; s < NS; ++s) {
    if (s + 2 < NS) {
      const int nxt = (cur + 2 >= 3) ? cur - 1 : cur + 2;
      STAGE2(nxt, (s + 2) * BK);
      if constexpr (BBF)
        asm volatile("s_waitcnt vmcnt(8)" ::: "memory");
      else
        asm volatile("s_waitcnt vmcnt(0) lgkmcnt(0)" ::: "memory");
    } else if (s + 2 == NS) {
      if constexpr (BBF)
        asm volatile("s_waitcnt vmcnt(4)" ::: "memory");
      else
        asm volatile("s_waitcnt vmcnt(0) lgkmcnt(0)" ::: "memory");
    } else {
      asm volatile("s_waitcnt vmcnt(0) lgkmcnt(0)" ::: "memory");
    }
    __builtin_amdgcn_s_barrier();
    asm volatile("" ::: "memory");

    bf16x8 af[4], bf[4];
#pragma unroll
    for (int i = 0; i < 4; ++i) {
      af[i] = *(const bf16x8*)&sA[cur][aIdx[i]];
      bf[i] = *(const bf16x8*)&sB[cur][bIdx[i]];
    }
    __builtin_amdgcn_s_setprio(1);
#pragma unroll
    for (int mr = 0; mr < 4; ++mr)
#pragma unroll
      for (int nr = 0; nr < 4; ++nr)
        acc[mr][nr] = __builtin_amdgcn_mfma_f32_16x16x32_bf16(
            af[mr], bf[nr], acc[mr][nr], 0, 0, 0);
    __builtin_amdgcn_s_setprio(0);
    asm volatile("" ::: "memory");
    __builtin_amdgcn_s_barrier();
    cur = (cur + 1 >= 3) ? 0 : cur + 1;
  }

#pragma unroll
  for (int mr = 0; mr < 4; ++mr) {
#pragma unroll
    for (int j = 0; j < 4; ++j) {
      const int row = wm + mr * 16 + kq * 4 + j;
      if (row < mValid) {
        const int tok = sTok[row];
        const float w = sWgt[row];
        float* dst = out + (size_t)tok * H_DIM + nbase + wn + rl;
#pragma unroll
        for (int nr = 0; nr < 4; ++nr)
          unsafeAtomicAdd(dst + nr * 16, w * acc[mr][nr][j]);
      }
    }
  }
#undef STAGE2
}

// ---------------------------------------------------------------------------
extern "C" void kernel_launch(void* const* d_in, const int* in_sizes, int n_in,
                              void* d_out, int out_size, void* d_ws,
                              size_t ws_size, hipStream_t stream) {
  const float* x  = (const float*)d_in[0];
  const float* gw = (const float*)d_in[1];
  const float* w1 = (const float*)d_in[2];
  const float* w3 = (const float*)d_in[3];
  const float* w2 = (const float*)d_in[4];
  float* out = (float*)d_out;                  // [T, H]
  float* logits = out + (size_t)T_TOK * H_DIM; // [T, E]

  char* ws = (char*)d_ws;
  const size_t HDR = 1u << 20;
  const size_t XB_SZ = (size_t)T_TOK * H_DIM * 2;           // 32 MiB
  const size_t HB_SZ = (size_t)MAXPAIR * F_DIM * 2;         // 128 MiB
  const size_t W_SZ  = (size_t)E_NUM * F_DIM * H_DIM * 2;   // 128 MiB each

  int* ctrl = (int*)(ws);                      // 4 KB (flags at ctrl+512)
  int* tIdx = (int*)(ws + 4096);
  float* tW = (float*)(ws + 4096 + 65536);
  int* pairTok = (int*)(ws + 4096 + 131072);
  float* pairWgt = (float*)(ws + 4096 + 196608);
  unsigned short* xb = (unsigned short*)(ws + HDR);
  unsigned short* hbuf = (unsigned short*)(ws + HDR + XB_SZ);
  unsigned short* w1b = (unsigned short*)(ws + HDR + XB_SZ + HB_SZ);
  unsigned short* w3b = w1b + W_SZ / 2;
  unsigned short* w2b = w3b + W_SZ / 2;

  const bool cw13 = ws_size >= HDR + XB_SZ + HB_SZ + 2 * W_SZ;
  const bool cw2  = ws_size >= HDR + XB_SZ + HB_SZ + 3 * W_SZ;

  hipMemsetAsync(ctrl, 0, 4096, stream);
  hipMemsetAsync(out, 0, (size_t)T_TOK * H_DIM * sizeof(float), stream);

  router_kernel<<<T_TOK / 4, 256, 0, stream>>>(x, gw, logits, xb, ctrl, tIdx, tW);
  plan_kernel<<<1, 256, 0, stream>>>(ctrl);
  scatter_kernel<<<T_TOK / 256, 256, 0, stream>>>(tIdx, tW, ctrl, pairTok, pairWgt);

  const int NG = MAX_MT * 32;  // 4352 gemm blocks
  if (cw13) {
    const int nconv = cw2 ? NCONV : 0;
    gemm1_kernel<1><<<NG + nconv, 256, 0, stream>>>(
        w1, w3, w1b, w3b, xb, ctrl, ctrl + 512, pairTok, hbuf, w2, w2b, nconv);
  } else {
    gemm1_kernel<0><<<NG, 256, 0, stream>>>(
        w1, w3, w1b, w3b, xb, ctrl, ctrl + 512, pairTok, hbuf, w2, w2b, 0);
  }
  if (cw2)
    gemm2_kernel<1><<<MAX_MT * 16, 256, 0, stream>>>(w2, w2b, hbuf, ctrl,
                                                     pairTok, pairWgt, out);
  else
    gemm2_kernel<0><<<MAX_MT * 16, 256, 0, stream>>>(w2, w2b, hbuf, ctrl,
                                                     pairTok, pairWgt, out);
}

// Round 8
// 1632.659 us; speedup vs baseline: 3.1134x; 3.1134x over previous
//
#include <hip/hip_runtime.h>
#include <math.h>

#define T_TOK 8192
#define H_DIM 2048
#define F_DIM 4096
#define E_NUM 8
#define MAXPAIR (T_TOK * 2)
#define MAX_MT 136
#define BM 128
#define BN 128
#define BK 32
#define BN2 256
#define NCONV 2048  // w2-convert blocks fused into gemm1 dispatch

typedef __attribute__((ext_vector_type(4))) float f32x4;
typedef __attribute__((ext_vector_type(8))) short s16x8;
typedef __attribute__((ext_vector_type(8))) __bf16 bf16x8;
typedef __attribute__((ext_vector_type(4))) unsigned short u16x4;

__device__ __forceinline__ unsigned short f2bf(float f) {
  unsigned int u = __float_as_uint(f);
  u += 0x7FFFu + ((u >> 16) & 1u);
  return (unsigned short)(u >> 16);
}

__device__ __forceinline__ s16x8 pack8(f32x4 a, f32x4 b) {
  s16x8 r;
  r[0] = (short)f2bf(a.x); r[1] = (short)f2bf(a.y);
  r[2] = (short)f2bf(a.z); r[3] = (short)f2bf(a.w);
  r[4] = (short)f2bf(b.x); r[5] = (short)f2bf(b.y);
  r[6] = (short)f2bf(b.z); r[7] = (short)f2bf(b.w);
  return r;
}

#define GLD16(gsrc, ldst)                                                      \
  __builtin_amdgcn_global_load_lds(                                            \
      (__attribute__((address_space(1))) void*)(gsrc),                         \
      (__attribute__((address_space(3))) void*)(ldst), 16, 0, 0)

// ---------------------------------------------------------------------------
// fp32 -> bf16 conversion for w1 AND w3 in one dispatch (memory-bound)
// ---------------------------------------------------------------------------
__global__ __launch_bounds__(256) void convert2_kernel(
    const float* __restrict__ s1, unsigned short* __restrict__ d1,
    const float* __restrict__ s2, unsigned short* __restrict__ d2,
    long long n8) {
  const int half = gridDim.x / 2;
  const float* src = (blockIdx.x < half) ? s1 : s2;
  unsigned short* dst = (blockIdx.x < half) ? d1 : d2;
  const int bid = (blockIdx.x < half) ? blockIdx.x : blockIdx.x - half;
  long long i = (long long)bid * 256 + threadIdx.x;
  const long long stride = (long long)half * 256;
  for (; i < n8; i += stride) {
    f32x4 a = *(const f32x4*)(src + i * 8);
    f32x4 b = *(const f32x4*)(src + i * 8 + 4);
    *(s16x8*)(dst + i * 8) = pack8(a, b);
  }
}

// ---------------------------------------------------------------------------
// Router: logits (fp32, exact) + x->bf16 conversion + top2 + counts
// ---------------------------------------------------------------------------
__global__ __launch_bounds__(256) void router_kernel(
    const float* __restrict__ x, const float* __restrict__ gw,
    float* __restrict__ logits, unsigned short* __restrict__ xb,
    int* __restrict__ ctrl, int* __restrict__ tIdx, float* __restrict__ tW) {
  const int wid = threadIdx.x >> 6, lane = threadIdx.x & 63;
  const int t = blockIdx.x * 4 + wid;
  const float* xr = x + (size_t)t * H_DIM;
  float acc[E_NUM];
#pragma unroll
  for (int e = 0; e < E_NUM; ++e) acc[e] = 0.f;
#pragma unroll
  for (int c = 0; c < H_DIM / 256; ++c) {
    const int h0 = c * 256 + lane * 4;
    f32x4 xv = *(const f32x4*)(xr + h0);
    u16x4 p;
    p.x = f2bf(xv.x); p.y = f2bf(xv.y); p.z = f2bf(xv.z); p.w = f2bf(xv.w);
    *(u16x4*)(xb + (size_t)t * H_DIM + h0) = p;
#pragma unroll
    for (int e = 0; e < E_NUM; ++e) {
      f32x4 gv = *(const f32x4*)(gw + (size_t)e * H_DIM + h0);
      acc[e] += xv.x * gv.x + xv.y * gv.y + xv.z * gv.z + xv.w * gv.w;
    }
  }
#pragma unroll
  for (int e = 0; e < E_NUM; ++e) {
#pragma unroll
    for (int off = 32; off >= 1; off >>= 1) acc[e] += __shfl_xor(acc[e], off, 64);
  }
  if (lane == 0) {
#pragma unroll
    for (int e = 0; e < E_NUM; ++e) logits[(size_t)t * E_NUM + e] = acc[e];
    int i0 = 0;
    float m0 = acc[0];
    for (int e = 1; e < E_NUM; ++e)
      if (acc[e] > m0) { m0 = acc[e]; i0 = e; }
    int i1 = -1;
    float m1 = -3.4e38f;
    for (int e = 0; e < E_NUM; ++e)
      if (e != i0 && acc[e] > m1) { m1 = acc[e]; i1 = e; }
    float ex = expf(m1 - m0);
    float w0 = 1.f / (1.f + ex);
    float w1 = ex * w0;
    tIdx[t * 2] = i0; tIdx[t * 2 + 1] = i1;
    tW[t * 2] = w0;  tW[t * 2 + 1] = w1;
    atomicAdd(&ctrl[i0], 1);
    atomicAdd(&ctrl[i1], 1);
  }
}

// ---------------------------------------------------------------------------
// Plan (parallel): offsets, cursors, flat M-tile map
// ---------------------------------------------------------------------------
__global__ __launch_bounds__(256) void plan_kernel(int* __restrict__ ctrl) {
  __shared__ int cnt[E_NUM], offs[E_NUM + 1], tbase[E_NUM + 1];
  const int t = threadIdx.x;
  if (t < E_NUM) cnt[t] = ctrl[t];
  __syncthreads();
  if (t == 0) {
    int off = 0, mt = 0;
    for (int e = 0; e < E_NUM; ++e) {
      offs[e] = off; tbase[e] = mt;
      ctrl[8 + e] = off;
      ctrl[16 + e] = off;
      off += cnt[e];
      mt += (cnt[e] + BM - 1) / BM;
    }
    offs[E_NUM] = off; tbase[E_NUM] = mt;
    ctrl[24] = mt;
  }
  __syncthreads();
  const int total = tbase[E_NUM];
  for (int i = t; i < total; i += 256) {
    int e = 0;
    while (tbase[e + 1] <= i) ++e;
    ctrl[32 + i] = e;
    ctrl[32 + MAX_MT + i] = offs[e] + (i - tbase[e]) * BM;
  }
}

__global__ __launch_bounds__(256) void scatter_kernel(
    const int* __restrict__ tIdx, const float* __restrict__ tW,
    int* __restrict__ ctrl, int* __restrict__ pairTok,
    float* __restrict__ pairWgt) {
  const int t = blockIdx.x * 256 + threadIdx.x;
  if (t >= T_TOK) return;
#pragma unroll
  for (int j = 0; j < 2; ++j) {
    const int e = tIdx[t * 2 + j];
    const int pos = atomicAdd(&ctrl[16 + e], 1);
    pairTok[pos] = t;
    pairWgt[pos] = tW[t * 2 + j];
  }
}

// ---------------------------------------------------------------------------
// GEMM1: h = silu(x·w1^T) * (x·w3^T)  (bf16 out)  — round-5 verified
// 3-buffer depth-2 counted vmcnt(12), raw barriers, setprio.
// w2-convert blocks fused 1-per-3 among gemm blocks.
// ---------------------------------------------------------------------------
template <int BBF>
__global__ __launch_bounds__(256, 2) void gemm1_kernel(
    const float* __restrict__ w1f, const float* __restrict__ w3f,
    const unsigned short* __restrict__ w1b,
    const unsigned short* __restrict__ w3b,
    const unsigned short* __restrict__ xb, const int* __restrict__ ctrl,
    const int* __restrict__ pairTok, unsigned short* __restrict__ hbuf,
    const float* __restrict__ w2f, unsigned short* __restrict__ w2b,
    int nconv) {
  int gid = blockIdx.x;
  const int nconv3 = nconv * 3;
  if (gid < nconv3) {
    if ((gid % 3) == 2) {
      const int cid = gid / 3;
      const long long per = (long long)E_NUM * F_DIM * H_DIM / 8 / NCONV;
      long long i = (long long)cid * per + threadIdx.x;
      const long long end = (long long)(cid + 1) * per;
      for (; i < end; i += 256) {
        f32x4 a = *(const f32x4*)(w2f + i * 8);
        f32x4 b = *(const f32x4*)(w2f + i * 8 + 4);
        *(s16x8*)(w2b + i * 8) = pack8(a, b);
      }
      return;
    }
    gid = gid - (gid + 1) / 3;
  } else {
    gid = gid - nconv;
  }

  const int mtTotal = ctrl[24];
  const int mt = gid >> 5;   // nt-major: same-weight-tile blocks 32 apart
  const int nt = gid & 31;   // -> same XCD -> L2 reuse
  if (mt >= mtTotal) return;
  const int e = ctrl[32 + mt];
  const int mbase = ctrl[32 + MAX_MT + mt];
  int mValid = ctrl[8 + e] + ctrl[e] - mbase;
  if (mValid > BM) mValid = BM;
  const int nbase = nt * BN;

  __shared__ __align__(16) short sA[3][BM * BK];
  __shared__ __align__(16) short sB1[3][BM * BK];
  __shared__ __align__(16) short sB3[3][BM * BK];
  __shared__ int sTok[BM];

  const int tid = threadIdx.x;
  if (tid < BM) sTok[tid] = pairTok[mbase + (tid < mValid ? tid : 0)];
  __syncthreads();

  const int c0 = tid, c1 = tid + 256;
  const int r0 = c0 >> 2, r1 = c1 >> 2;
  const int kg0 = (c0 & 3) ^ ((r0 >> 1) & 3);
  const int kg1 = (c1 & 3) ^ ((r1 >> 1) & 3);

  const unsigned short* srcA0 = xb + (size_t)sTok[r0] * H_DIM + kg0 * 8;
  const unsigned short* srcA1 = xb + (size_t)sTok[r1] * H_DIM + kg1 * 8;
  const size_t wbase = (size_t)e * F_DIM * H_DIM;
  const float *f10, *f11, *f30, *f31;
  const unsigned short *p10, *p11, *p30, *p31;
  if constexpr (BBF) {
    p10 = w1b + wbase + (size_t)(nbase + r0) * H_DIM + kg0 * 8;
    p11 = w1b + wbase + (size_t)(nbase + r1) * H_DIM + kg1 * 8;
    p30 = w3b + wbase + (size_t)(nbase + r0) * H_DIM + kg0 * 8;
    p31 = w3b + wbase + (size_t)(nbase + r1) * H_DIM + kg1 * 8;
  } else {
    f10 = w1f + wbase + (size_t)(nbase + r0) * H_DIM + kg0 * 8;
    f11 = w1f + wbase + (size_t)(nbase + r1) * H_DIM + kg1 * 8;
    f30 = w3f + wbase + (size_t)(nbase + r0) * H_DIM + kg0 * 8;
    f31 = w3f + wbase + (size_t)(nbase + r1) * H_DIM + kg1 * 8;
  }

  f32x4 acc1[4][4], acc3[4][4];
  const f32x4 fz = {0.f, 0.f, 0.f, 0.f};
#pragma unroll
  for (int i = 0; i < 4; ++i)
#pragma unroll
    for (int j = 0; j < 4; ++j) { acc1[i][j] = fz; acc3[i][j] = fz; }

  const int lane = tid & 63, wid = tid >> 6;
  const int wm = (wid >> 1) * 64, wn = (wid & 1) * 64;
  const int rl = lane & 15, kq = lane >> 4;

  int aIdx[4], bIdx[4];
#pragma unroll
  for (int i = 0; i < 4; ++i) {
    const int ra = wm + i * 16 + rl;
    aIdx[i] = ra * BK + ((kq ^ ((ra >> 1) & 3)) * 8);
    const int rb = wn + i * 16 + rl;
    bIdx[i] = rb * BK + ((kq ^ ((rb >> 1) & 3)) * 8);
  }

#define STAGE1(buf, k0)                                                        \
  {                                                                            \
    GLD16(srcA0 + (k0), &sA[buf][c0 * 8]);                                     \
    GLD16(srcA1 + (k0), &sA[buf][c1 * 8]);                                     \
    if constexpr (BBF) {                                                       \
      GLD16(p10 + (k0), &sB1[buf][c0 * 8]);                                    \
      GLD16(p11 + (k0), &sB1[buf][c1 * 8]);                                    \
      GLD16(p30 + (k0), &sB3[buf][c0 * 8]);                                    \
      GLD16(p31 + (k0), &sB3[buf][c1 * 8]);                                    \
    } else {                                                                   \
      f32x4 t0 = *(const f32x4*)(f10 + (k0));                                  \
      f32x4 t1 = *(const f32x4*)(f10 + (k0) + 4);                              \
      *(s16x8*)&sB1[buf][c0 * 8] = pack8(t0, t1);                              \
      t0 = *(const f32x4*)(f11 + (k0));                                        \
      t1 = *(const f32x4*)(f11 + (k0) + 4);                                    \
      *(s16x8*)&sB1[buf][c1 * 8] = pack8(t0, t1);                              \
      t0 = *(const f32x4*)(f30 + (k0));                                        \
      t1 = *(const f32x4*)(f30 + (k0) + 4);                                    \
      *(s16x8*)&sB3[buf][c0 * 8] = pack8(t0, t1);                              \
      t0 = *(const f32x4*)(f31 + (k0));                                        \
      t1 = *(const f32x4*)(f31 + (k0) + 4);                                    \
      *(s16x8*)&sB3[buf][c1 * 8] = pack8(t0, t1);                              \
    }                                                                          \
  }

  STAGE1(0, 0);
  STAGE1(1, BK);

  const int NS = H_DIM / BK;  // 64
  int cur = 0;
  for (int s = 0; s < NS; ++s) {
    if (s + 2 < NS) {
      const int nxt = (cur + 2 >= 3) ? cur - 1 : cur + 2;
      STAGE1(nxt, (s + 2) * BK);
      if constexpr (BBF)
        asm volatile("s_waitcnt vmcnt(12)" ::: "memory");
      else
        asm volatile("s_waitcnt vmcnt(0) lgkmcnt(0)" ::: "memory");
    } else if (s + 2 == NS) {
      if constexpr (BBF)
        asm volatile("s_waitcnt vmcnt(6)" ::: "memory");
      else
        asm volatile("s_waitcnt vmcnt(0) lgkmcnt(0)" ::: "memory");
    } else {
      asm volatile("s_waitcnt vmcnt(0) lgkmcnt(0)" ::: "memory");
    }
    __builtin_amdgcn_s_barrier();
    asm volatile("" ::: "memory");

    bf16x8 af[4], bf1[4], bf3[4];
#pragma unroll
    for (int i = 0; i < 4; ++i) {
      af[i] = *(const bf16x8*)&sA[cur][aIdx[i]];
      bf1[i] = *(const bf16x8*)&sB1[cur][bIdx[i]];
      bf3[i] = *(const bf16x8*)&sB3[cur][bIdx[i]];
    }
    __builtin_amdgcn_s_setprio(1);
#pragma unroll
    for (int mr = 0; mr < 4; ++mr)
#pragma unroll
      for (int nr = 0; nr < 4; ++nr) {
        acc1[mr][nr] = __builtin_amdgcn_mfma_f32_16x16x32_bf16(
            af[mr], bf1[nr], acc1[mr][nr], 0, 0, 0);
        acc3[mr][nr] = __builtin_amdgcn_mfma_f32_16x16x32_bf16(
            af[mr], bf3[nr], acc3[mr][nr], 0, 0, 0);
      }
    __builtin_amdgcn_s_setprio(0);
    asm volatile("" ::: "memory");
    __builtin_amdgcn_s_barrier();
    cur = (cur + 1 >= 3) ? 0 : cur + 1;
  }

#pragma unroll
  for (int mr = 0; mr < 4; ++mr) {
#pragma unroll
    for (int j = 0; j < 4; ++j) {
      const int row = wm + mr * 16 + kq * 4 + j;
      if (row < mValid) {
        unsigned short* dst =
            hbuf + (size_t)(mbase + row) * F_DIM + nbase + wn + rl;
#pragma unroll
        for (int nr = 0; nr < 4; ++nr) {
          const float z = acc1[mr][nr][j];
          const float hv = (z / (1.f + expf(-z))) * acc3[mr][nr][j];
          dst[nr * 16] = f2bf(hv);
        }
      }
    }
  }
#undef STAGE1
}

// ---------------------------------------------------------------------------
// GEMM2: out[tok] += wgt * (h·w2^T)
// Widened: BM=128 x BN2=256 x BK=32, 4 waves (2x2) of 64x128 each,
// acc[4][8]. 32 MFMA per K-step vs 16 before -> 2x compute density per
// staging/barrier. Same 3-buffer depth-2 vmcnt(12) pipeline (6 loads/stage).
// ---------------------------------------------------------------------------
template <int BBF>
__global__ __launch_bounds__(256, 2) void gemm2_kernel(
    const float* __restrict__ w2f, const unsigned short* __restrict__ w2b,
    const unsigned short* __restrict__ hbuf, const int* __restrict__ ctrl,
    const int* __restrict__ pairTok, const float* __restrict__ pairWgt,
    float* __restrict__ out) {
  const int mtTotal = ctrl[24];
  const int mt = blockIdx.x >> 3;  // nt-major: same-nt blocks 8 apart
  const int nt = blockIdx.x & 7;   // -> same XCD -> w2 slice L2-resident
  if (mt >= mtTotal) return;
  const int e = ctrl[32 + mt];
  const int mbase = ctrl[32 + MAX_MT + mt];
  int mValid = ctrl[8 + e] + ctrl[e] - mbase;
  if (mValid > BM) mValid = BM;
  const int nbase = nt * BN2;

  __shared__ __align__(16) short sA[3][BM * BK];    // 24 KB
  __shared__ __align__(16) short sB[3][BN2 * BK];   // 48 KB
  __shared__ int sTok[BM];
  __shared__ float sWgt[BM];

  const int tid = threadIdx.x;
  if (tid < BM) {
    const int p = mbase + (tid < mValid ? tid : 0);
    sTok[tid] = pairTok[p];
    sWgt[tid] = pairWgt[p];
  }
  __syncthreads();

  const int c0 = tid, c1 = tid + 256;
  const int r0 = c0 >> 2, r1 = c1 >> 2;
  const int kg0 = (c0 & 3) ^ ((r0 >> 1) & 3);
  const int kg1 = (c1 & 3) ^ ((r1 >> 1) & 3);

  size_t pa0 = (size_t)(mbase + r0); if (pa0 > MAXPAIR - 1) pa0 = MAXPAIR - 1;
  size_t pa1 = (size_t)(mbase + r1); if (pa1 > MAXPAIR - 1) pa1 = MAXPAIR - 1;
  const unsigned short* srcA0 = hbuf + pa0 * F_DIM + kg0 * 8;
  const unsigned short* srcA1 = hbuf + pa1 * F_DIM + kg1 * 8;
  const size_t wbase = (size_t)e * H_DIM * F_DIM;

  // B chunks j=0..3: c = tid + j*256, row = c>>2 (0..255), kg = swizzled
  const float* fw[4];
  const unsigned short* pw[4];
#pragma unroll
  for (int j = 0; j < 4; ++j) {
    const int c = tid + j * 256;
    const int row = c >> 2;
    const int kg = (c & 3) ^ ((row >> 1) & 3);
    if constexpr (BBF)
      pw[j] = w2b + wbase + (size_t)(nbase + row) * F_DIM + kg * 8;
    else
      fw[j] = w2f + wbase + (size_t)(nbase + row) * F_DIM + kg * 8;
  }

  f32x4 acc[4][8];
  const f32x4 fz = {0.f, 0.f, 0.f, 0.f};
#pragma unroll
  for (int i = 0; i < 4; ++i)
#pragma unroll
    for (int j = 0; j < 8; ++j) acc[i][j] = fz;

  const int lane = tid & 63, wid = tid >> 6;
  const int wm = (wid >> 1) * 64, wn = (wid & 1) * 128;
  const int rl = lane & 15, kq = lane >> 4;

  int aIdx[4], bIdx[8];
#pragma unroll
  for (int i = 0; i < 4; ++i) {
    const int ra = wm + i * 16 + rl;
    aIdx[i] = ra * BK + ((kq ^ ((ra >> 1) & 3)) * 8);
  }
#pragma unroll
  for (int i = 0; i < 8; ++i) {
    const int rb = wn + i * 16 + rl;
    bIdx[i] = rb * BK + ((kq ^ ((rb >> 1) & 3)) * 8);
  }

#define STAGE2(buf, k0)                                                        \
  {                                                                            \
    GLD16(srcA0 + (k0), &sA[buf][c0 * 8]);                                     \
    GLD16(srcA1 + (k0), &sA[buf][c1 * 8]);                                     \
    if constexpr (BBF) {                                                       \
      _Pragma("unroll") for (int j = 0; j < 4; ++j)                            \
          GLD16(pw[j] + (k0), &sB[buf][(tid + j * 256) * 8]);                  \
    } else {                                                                   \
      _Pragma("unroll") for (int j = 0; j < 4; ++j) {                          \
        f32x4 t0 = *(const f32x4*)(fw[j] + (k0));                              \
        f32x4 t1 = *(const f32x4*)(fw[j] + (k0) + 4);                          \
        *(s16x8*)&sB[buf][(tid + j * 256) * 8] = pack8(t0, t1);                \
      }                                                                        \
    }                                                                          \
  }

  STAGE2(0, 0);
  STAGE2(1, BK);

  const int NS = F_DIM / BK;  // 128
  int cur = 0;
  for (int s = 0; s < NS; ++s) {
    if (s + 2 < NS) {
      const int nxt = (cur + 2 >= 3) ? cur - 1 : cur + 2;
      STAGE2(nxt, (s + 2) * BK);
      if constexpr (BBF)
        asm volatile("s_waitcnt vmcnt(12)" ::: "memory");
      else
        asm volatile("s_waitcnt vmcnt(0) lgkmcnt(0)" ::: "memory");
    } else if (s + 2 == NS) {
      if constexpr (BBF)
        asm volatile("s_waitcnt vmcnt(6)" ::: "memory");
      else
        asm volatile("s_waitcnt vmcnt(0) lgkmcnt(0)" ::: "memory");
    } else {
      asm volatile("s_waitcnt vmcnt(0) lgkmcnt(0)" ::: "memory");
    }
    __builtin_amdgcn_s_barrier();
    asm volatile("" ::: "memory");

    bf16x8 af[4], bf[8];
#pragma unroll
    for (int i = 0; i < 4; ++i) af[i] = *(const bf16x8*)&sA[cur][aIdx[i]];
#pragma unroll
    for (int i = 0; i < 8; ++i) bf[i] = *(const bf16x8*)&sB[cur][bIdx[i]];
    __builtin_amdgcn_s_setprio(1);
#pragma unroll
    for (int mr = 0; mr < 4; ++mr)
#pragma unroll
      for (int nr = 0; nr < 8; ++nr)
        acc[mr][nr] = __builtin_amdgcn_mfma_f32_16x16x32_bf16(
            af[mr], bf[nr], acc[mr][nr], 0, 0, 0);
    __builtin_amdgcn_s_setprio(0);
    asm volatile("" ::: "memory");
    __builtin_amdgcn_s_barrier();
    cur = (cur + 1 >= 3) ? 0 : cur + 1;
  }

#pragma unroll
  for (int mr = 0; mr < 4; ++mr) {
#pragma unroll
    for (int j = 0; j < 4; ++j) {
      const int row = wm + mr * 16 + kq * 4 + j;
      if (row < mValid) {
        const int tok = sTok[row];
        const float w = sWgt[row];
        float* dst = out + (size_t)tok * H_DIM + nbase + wn + rl;
#pragma unroll
        for (int nr = 0; nr < 8; ++nr)
          unsafeAtomicAdd(dst + nr * 16, w * acc[mr][nr][j]);
      }
    }
  }
#undef STAGE2
}

// ---------------------------------------------------------------------------
extern "C" void kernel_launch(void* const* d_in, const int* in_sizes, int n_in,
                              void* d_out, int out_size, void* d_ws,
                              size_t ws_size, hipStream_t stream) {
  const float* x  = (const float*)d_in[0];
  const float* gw = (const float*)d_in[1];
  const float* w1 = (const float*)d_in[2];
  const float* w3 = (const float*)d_in[3];
  const float* w2 = (const float*)d_in[4];
  float* out = (float*)d_out;                  // [T, H]
  float* logits = out + (size_t)T_TOK * H_DIM; // [T, E]

  char* ws = (char*)d_ws;
  const size_t HDR = 1u << 20;
  const size_t XB_SZ = (size_t)T_TOK * H_DIM * 2;           // 32 MiB
  const size_t HB_SZ = (size_t)MAXPAIR * F_DIM * 2;         // 128 MiB
  const size_t W_SZ  = (size_t)E_NUM * F_DIM * H_DIM * 2;   // 128 MiB each

  int* ctrl = (int*)(ws);
  int* tIdx = (int*)(ws + 4096);
  float* tW = (float*)(ws + 4096 + 65536);
  int* pairTok = (int*)(ws + 4096 + 131072);
  float* pairWgt = (float*)(ws + 4096 + 196608);
  unsigned short* xb = (unsigned short*)(ws + HDR);
  unsigned short* hbuf = (unsigned short*)(ws + HDR + XB_SZ);
  unsigned short* w1b = (unsigned short*)(ws + HDR + XB_SZ + HB_SZ);
  unsigned short* w3b = w1b + W_SZ / 2;
  unsigned short* w2b = w3b + W_SZ / 2;

  const bool cw13 = ws_size >= HDR + XB_SZ + HB_SZ + 2 * W_SZ;
  const bool cw2  = ws_size >= HDR + XB_SZ + HB_SZ + 3 * W_SZ;

  hipMemsetAsync(ctrl, 0, 4096, stream);
  hipMemsetAsync(out, 0, (size_t)T_TOK * H_DIM * sizeof(float), stream);

  const long long N8 = (long long)E_NUM * F_DIM * H_DIM / 8;
  if (cw13)
    convert2_kernel<<<4096, 256, 0, stream>>>(w1, w1b, w3, w3b, N8);
  // w2 convert fused into gemm1 dispatch.

  router_kernel<<<T_TOK / 4, 256, 0, stream>>>(x, gw, logits, xb, ctrl, tIdx, tW);
  plan_kernel<<<1, 256, 0, stream>>>(ctrl);
  scatter_kernel<<<T_TOK / 256, 256, 0, stream>>>(tIdx, tW, ctrl, pairTok, pairWgt);

  const int NG = MAX_MT * 32;  // 4352 gemm blocks
  if (cw13) {
    const int nconv = cw2 ? NCONV : 0;
    gemm1_kernel<1><<<NG + nconv, 256, 0, stream>>>(
        w1, w3, w1b, w3b, xb, ctrl, pairTok, hbuf, w2, w2b, nconv);
  } else {
    gemm1_kernel<0><<<NG, 256, 0, stream>>>(
        w1, w3, w1b, w3b, xb, ctrl, pairTok, hbuf, w2, w2b, 0);
  }
  if (cw2)
    gemm2_kernel<1><<<MAX_MT * 8, 256, 0, stream>>>(w2, w2b, hbuf, ctrl,
                                                    pairTok, pairWgt, out);
  else
    gemm2_kernel<0><<<MAX_MT * 8, 256, 0, stream>>>(w2, w2b, hbuf, ctrl,
                                                    pairTok, pairWgt, out);
}

// Round 9
// 1442.750 us; speedup vs baseline: 3.5233x; 1.1316x over previous
//
#include <hip/hip_runtime.h>
#include <math.h>

#define T_TOK 8192
#define H_DIM 2048
#define F_DIM 4096
#define E_NUM 8
#define MAXPAIR (T_TOK * 2)
#define MAX_MT 136
#define BM 128
#define BN 128
#define BK 32
#define NCONV 2048   // w2-convert blocks fused into gemm1 dispatch
#define NCONV13 4096 // w1/w3-convert blocks fused into router dispatch

typedef __attribute__((ext_vector_type(4))) float f32x4;
typedef __attribute__((ext_vector_type(8))) short s16x8;
typedef __attribute__((ext_vector_type(8))) __bf16 bf16x8;
typedef __attribute__((ext_vector_type(4))) unsigned short u16x4;

__device__ __forceinline__ unsigned short f2bf(float f) {
  unsigned int u = __float_as_uint(f);
  u += 0x7FFFu + ((u >> 16) & 1u);
  return (unsigned short)(u >> 16);
}

__device__ __forceinline__ s16x8 pack8(f32x4 a, f32x4 b) {
  s16x8 r;
  r[0] = (short)f2bf(a.x); r[1] = (short)f2bf(a.y);
  r[2] = (short)f2bf(a.z); r[3] = (short)f2bf(a.w);
  r[4] = (short)f2bf(b.x); r[5] = (short)f2bf(b.y);
  r[6] = (short)f2bf(b.z); r[7] = (short)f2bf(b.w);
  return r;
}

#define GLD16(gsrc, ldst)                                                      \
  __builtin_amdgcn_global_load_lds(                                            \
      (__attribute__((address_space(1))) void*)(gsrc),                         \
      (__attribute__((address_space(3))) void*)(ldst), 16, 0, 0)

// ---------------------------------------------------------------------------
// Router + fused w1/w3 fp32->bf16 converts (independent work, consumer is a
// LATER dispatch -> no flags/spin needed; same safe pattern as w2 fusion).
// 1-in-3 blocks do router work; 2-in-3 convert contiguous slabs of w1/w3.
// ---------------------------------------------------------------------------
__global__ __launch_bounds__(256) void router_conv_kernel(
    const float* __restrict__ x, const float* __restrict__ gw,
    float* __restrict__ logits, unsigned short* __restrict__ xb,
    int* __restrict__ ctrl, int* __restrict__ tIdx, float* __restrict__ tW,
    const float* __restrict__ w1f, unsigned short* __restrict__ w1b,
    const float* __restrict__ w3f, unsigned short* __restrict__ w3b,
    int nconv) {
  int rb = blockIdx.x;  // router block id
  if (nconv) {
    const int nz = nconv + nconv / 2;  // demux zone: 3 * (nconv/... ) blocks
    // zone layout: bid%3==2 -> router(bid/3); else convert(bid - floor((bid+1)/3))
    if (blockIdx.x < nconv * 3 / 2 * 3 / 3 + nconv) { /* fallthrough below */ }
    const int bid = blockIdx.x;
    if (bid < 6144) {  // 2048 router + 4096 convert interleaved
      if ((bid % 3) != 2) {
        const int cid = bid - (bid + 1) / 3;           // 0..4095
        const float* src = (cid < 2048) ? w1f : w3f;
        unsigned short* dst = (cid < 2048) ? w1b : w3b;
        const long long base = (long long)(cid & 2047) * 4096;
#pragma unroll
        for (int it = 0; it < 16; ++it) {
          const long long i = base + it * 256 + threadIdx.x;
          f32x4 a = *(const f32x4*)(src + i * 8);
          f32x4 b = *(const f32x4*)(src + i * 8 + 4);
          *(s16x8*)(dst + i * 8) = pack8(a, b);
        }
        return;
      }
      rb = bid / 3;  // 0..2047
    } else {
      return;  // (unused padding; grid is exactly 6144 when fused)
    }
    (void)nz;
  }

  const int wid = threadIdx.x >> 6, lane = threadIdx.x & 63;
  const int t = rb * 4 + wid;
  const float* xr = x + (size_t)t * H_DIM;
  float acc[E_NUM];
#pragma unroll
  for (int e = 0; e < E_NUM; ++e) acc[e] = 0.f;
#pragma unroll
  for (int c = 0; c < H_DIM / 256; ++c) {
    const int h0 = c * 256 + lane * 4;
    f32x4 xv = *(const f32x4*)(xr + h0);
    u16x4 p;
    p.x = f2bf(xv.x); p.y = f2bf(xv.y); p.z = f2bf(xv.z); p.w = f2bf(xv.w);
    *(u16x4*)(xb + (size_t)t * H_DIM + h0) = p;
#pragma unroll
    for (int e = 0; e < E_NUM; ++e) {
      f32x4 gv = *(const f32x4*)(gw + (size_t)e * H_DIM + h0);
      acc[e] += xv.x * gv.x + xv.y * gv.y + xv.z * gv.z + xv.w * gv.w;
    }
  }
#pragma unroll
  for (int e = 0; e < E_NUM; ++e) {
#pragma unroll
    for (int off = 32; off >= 1; off >>= 1) acc[e] += __shfl_xor(acc[e], off, 64);
  }
  if (lane == 0) {
#pragma unroll
    for (int e = 0; e < E_NUM; ++e) logits[(size_t)t * E_NUM + e] = acc[e];
    int i0 = 0;
    float m0 = acc[0];
    for (int e = 1; e < E_NUM; ++e)
      if (acc[e] > m0) { m0 = acc[e]; i0 = e; }
    int i1 = -1;
    float m1 = -3.4e38f;
    for (int e = 0; e < E_NUM; ++e)
      if (e != i0 && acc[e] > m1) { m1 = acc[e]; i1 = e; }
    float ex = expf(m1 - m0);
    float w0 = 1.f / (1.f + ex);
    float w1 = ex * w0;
    tIdx[t * 2] = i0; tIdx[t * 2 + 1] = i1;
    tW[t * 2] = w0;  tW[t * 2 + 1] = w1;
    atomicAdd(&ctrl[i0], 1);
    atomicAdd(&ctrl[i1], 1);
  }
}

// ---------------------------------------------------------------------------
// Plan (parallel): offsets, cursors, flat M-tile map
// ---------------------------------------------------------------------------
__global__ __launch_bounds__(256) void plan_kernel(int* __restrict__ ctrl) {
  __shared__ int cnt[E_NUM], offs[E_NUM + 1], tbase[E_NUM + 1];
  const int t = threadIdx.x;
  if (t < E_NUM) cnt[t] = ctrl[t];
  __syncthreads();
  if (t == 0) {
    int off = 0, mt = 0;
    for (int e = 0; e < E_NUM; ++e) {
      offs[e] = off; tbase[e] = mt;
      ctrl[8 + e] = off;
      ctrl[16 + e] = off;
      off += cnt[e];
      mt += (cnt[e] + BM - 1) / BM;
    }
    offs[E_NUM] = off; tbase[E_NUM] = mt;
    ctrl[24] = mt;
  }
  __syncthreads();
  const int total = tbase[E_NUM];
  for (int i = t; i < total; i += 256) {
    int e = 0;
    while (tbase[e + 1] <= i) ++e;
    ctrl[32 + i] = e;
    ctrl[32 + MAX_MT + i] = offs[e] + (i - tbase[e]) * BM;
  }
}

__global__ __launch_bounds__(256) void scatter_kernel(
    const int* __restrict__ tIdx, const float* __restrict__ tW,
    int* __restrict__ ctrl, int* __restrict__ pairTok,
    float* __restrict__ pairWgt) {
  const int t = blockIdx.x * 256 + threadIdx.x;
  if (t >= T_TOK) return;
#pragma unroll
  for (int j = 0; j < 2; ++j) {
    const int e = tIdx[t * 2 + j];
    const int pos = atomicAdd(&ctrl[16 + e], 1);
    pairTok[pos] = t;
    pairWgt[pos] = tW[t * 2 + j];
  }
}

// ---------------------------------------------------------------------------
// GEMM1: h = silu(x·w1^T) * (x·w3^T)  (bf16 out)  — round-5 verified
// 3-buffer depth-2 counted vmcnt(12), raw barriers, setprio.
// w2-convert blocks fused 1-per-3 among gemm blocks.
// ---------------------------------------------------------------------------
template <int BBF>
__global__ __launch_bounds__(256, 2) void gemm1_kernel(
    const float* __restrict__ w1f, const float* __restrict__ w3f,
    const unsigned short* __restrict__ w1b,
    const unsigned short* __restrict__ w3b,
    const unsigned short* __restrict__ xb, const int* __restrict__ ctrl,
    const int* __restrict__ pairTok, unsigned short* __restrict__ hbuf,
    const float* __restrict__ w2f, unsigned short* __restrict__ w2b,
    int nconv) {
  int gid = blockIdx.x;
  const int nconv3 = nconv * 3;
  if (gid < nconv3) {
    if ((gid % 3) == 2) {
      const int cid = gid / 3;
      const long long per = (long long)E_NUM * F_DIM * H_DIM / 8 / NCONV;
      long long i = (long long)cid * per + threadIdx.x;
      const long long end = (long long)(cid + 1) * per;
      for (; i < end; i += 256) {
        f32x4 a = *(const f32x4*)(w2f + i * 8);
        f32x4 b = *(const f32x4*)(w2f + i * 8 + 4);
        *(s16x8*)(w2b + i * 8) = pack8(a, b);
      }
      return;
    }
    gid = gid - (gid + 1) / 3;
  } else {
    gid = gid - nconv;
  }

  const int mtTotal = ctrl[24];
  const int mt = gid >> 5;   // nt-major: same-weight-tile blocks 32 apart
  const int nt = gid & 31;   // -> same XCD -> L2 reuse
  if (mt >= mtTotal) return;
  const int e = ctrl[32 + mt];
  const int mbase = ctrl[32 + MAX_MT + mt];
  int mValid = ctrl[8 + e] + ctrl[e] - mbase;
  if (mValid > BM) mValid = BM;
  const int nbase = nt * BN;

  __shared__ __align__(16) short sA[3][BM * BK];
  __shared__ __align__(16) short sB1[3][BM * BK];
  __shared__ __align__(16) short sB3[3][BM * BK];
  __shared__ int sTok[BM];

  const int tid = threadIdx.x;
  if (tid < BM) sTok[tid] = pairTok[mbase + (tid < mValid ? tid : 0)];
  __syncthreads();

  const int c0 = tid, c1 = tid + 256;
  const int r0 = c0 >> 2, r1 = c1 >> 2;
  const int kg0 = (c0 & 3) ^ ((r0 >> 1) & 3);
  const int kg1 = (c1 & 3) ^ ((r1 >> 1) & 3);

  const unsigned short* srcA0 = xb + (size_t)sTok[r0] * H_DIM + kg0 * 8;
  const unsigned short* srcA1 = xb + (size_t)sTok[r1] * H_DIM + kg1 * 8;
  const size_t wbase = (size_t)e * F_DIM * H_DIM;
  const float *f10, *f11, *f30, *f31;
  const unsigned short *p10, *p11, *p30, *p31;
  if constexpr (BBF) {
    p10 = w1b + wbase + (size_t)(nbase + r0) * H_DIM + kg0 * 8;
    p11 = w1b + wbase + (size_t)(nbase + r1) * H_DIM + kg1 * 8;
    p30 = w3b + wbase + (size_t)(nbase + r0) * H_DIM + kg0 * 8;
    p31 = w3b + wbase + (size_t)(nbase + r1) * H_DIM + kg1 * 8;
  } else {
    f10 = w1f + wbase + (size_t)(nbase + r0) * H_DIM + kg0 * 8;
    f11 = w1f + wbase + (size_t)(nbase + r1) * H_DIM + kg1 * 8;
    f30 = w3f + wbase + (size_t)(nbase + r0) * H_DIM + kg0 * 8;
    f31 = w3f + wbase + (size_t)(nbase + r1) * H_DIM + kg1 * 8;
  }

  f32x4 acc1[4][4], acc3[4][4];
  const f32x4 fz = {0.f, 0.f, 0.f, 0.f};
#pragma unroll
  for (int i = 0; i < 4; ++i)
#pragma unroll
    for (int j = 0; j < 4; ++j) { acc1[i][j] = fz; acc3[i][j] = fz; }

  const int lane = tid & 63, wid = tid >> 6;
  const int wm = (wid >> 1) * 64, wn = (wid & 1) * 64;
  const int rl = lane & 15, kq = lane >> 4;

  int aIdx[4], bIdx[4];
#pragma unroll
  for (int i = 0; i < 4; ++i) {
    const int ra = wm + i * 16 + rl;
    aIdx[i] = ra * BK + ((kq ^ ((ra >> 1) & 3)) * 8);
    const int rb = wn + i * 16 + rl;
    bIdx[i] = rb * BK + ((kq ^ ((rb >> 1) & 3)) * 8);
  }

#define STAGE1(buf, k0)                                                        \
  {                                                                            \
    GLD16(srcA0 + (k0), &sA[buf][c0 * 8]);                                     \
    GLD16(srcA1 + (k0), &sA[buf][c1 * 8]);                                     \
    if constexpr (BBF) {                                                       \
      GLD16(p10 + (k0), &sB1[buf][c0 * 8]);                                    \
      GLD16(p11 + (k0), &sB1[buf][c1 * 8]);                                    \
      GLD16(p30 + (k0), &sB3[buf][c0 * 8]);                                    \
      GLD16(p31 + (k0), &sB3[buf][c1 * 8]);                                    \
    } else {                                                                   \
      f32x4 t0 = *(const f32x4*)(f10 + (k0));                                  \
      f32x4 t1 = *(const f32x4*)(f10 + (k0) + 4);                              \
      *(s16x8*)&sB1[buf][c0 * 8] = pack8(t0, t1);                              \
      t0 = *(const f32x4*)(f11 + (k0));                                        \
      t1 = *(const f32x4*)(f11 + (k0) + 4);                                    \
      *(s16x8*)&sB1[buf][c1 * 8] = pack8(t0, t1);                              \
      t0 = *(const f32x4*)(f30 + (k0));                                        \
      t1 = *(const f32x4*)(f30 + (k0) + 4);                                    \
      *(s16x8*)&sB3[buf][c0 * 8] = pack8(t0, t1);                              \
      t0 = *(const f32x4*)(f31 + (k0));                                        \
      t1 = *(const f32x4*)(f31 + (k0) + 4);                                    \
      *(s16x8*)&sB3[buf][c1 * 8] = pack8(t0, t1);                              \
    }                                                                          \
  }

  STAGE1(0, 0);
  STAGE1(1, BK);

  const int NS = H_DIM / BK;  // 64
  int cur = 0;
  for (int s = 0; s < NS; ++s) {
    if (s + 2 < NS) {
      const int nxt = (cur + 2 >= 3) ? cur - 1 : cur + 2;
      STAGE1(nxt, (s + 2) * BK);
      if constexpr (BBF)
        asm volatile("s_waitcnt vmcnt(12)" ::: "memory");
      else
        asm volatile("s_waitcnt vmcnt(0) lgkmcnt(0)" ::: "memory");
    } else if (s + 2 == NS) {
      if constexpr (BBF)
        asm volatile("s_waitcnt vmcnt(6)" ::: "memory");
      else
        asm volatile("s_waitcnt vmcnt(0) lgkmcnt(0)" ::: "memory");
    } else {
      asm volatile("s_waitcnt vmcnt(0) lgkmcnt(0)" ::: "memory");
    }
    __builtin_amdgcn_s_barrier();
    asm volatile("" ::: "memory");

    bf16x8 af[4], bf1[4], bf3[4];
#pragma unroll
    for (int i = 0; i < 4; ++i) {
      af[i] = *(const bf16x8*)&sA[cur][aIdx[i]];
      bf1[i] = *(const bf16x8*)&sB1[cur][bIdx[i]];
      bf3[i] = *(const bf16x8*)&sB3[cur][bIdx[i]];
    }
    __builtin_amdgcn_s_setprio(1);
#pragma unroll
    for (int mr = 0; mr < 4; ++mr)
#pragma unroll
      for (int nr = 0; nr < 4; ++nr) {
        acc1[mr][nr] = __builtin_amdgcn_mfma_f32_16x16x32_bf16(
            af[mr], bf1[nr], acc1[mr][nr], 0, 0, 0);
        acc3[mr][nr] = __builtin_amdgcn_mfma_f32_16x16x32_bf16(
            af[mr], bf3[nr], acc3[mr][nr], 0, 0, 0);
      }
    __builtin_amdgcn_s_setprio(0);
    asm volatile("" ::: "memory");
    __builtin_amdgcn_s_barrier();
    cur = (cur + 1 >= 3) ? 0 : cur + 1;
  }

#pragma unroll
  for (int mr = 0; mr < 4; ++mr) {
#pragma unroll
    for (int j = 0; j < 4; ++j) {
      const int row = wm + mr * 16 + kq * 4 + j;
      if (row < mValid) {
        unsigned short* dst =
            hbuf + (size_t)(mbase + row) * F_DIM + nbase + wn + rl;
#pragma unroll
        for (int nr = 0; nr < 4; ++nr) {
          const float z = acc1[mr][nr][j];
          const float hv = (z / (1.f + expf(-z))) * acc3[mr][nr][j];
          dst[nr * 16] = f2bf(hv);
        }
      }
    }
  }
#undef STAGE1
}

// ---------------------------------------------------------------------------
// GEMM2: out[tok] += wgt * (h·w2^T)   (round-5 verified pipeline, BN=128)
// ---------------------------------------------------------------------------
template <int BBF>
__global__ __launch_bounds__(256, 2) void gemm2_kernel(
    const float* __restrict__ w2f, const unsigned short* __restrict__ w2b,
    const unsigned short* __restrict__ hbuf, const int* __restrict__ ctrl,
    const int* __restrict__ pairTok, const float* __restrict__ pairWgt,
    float* __restrict__ out) {
  const int mtTotal = ctrl[24];
  const int mt = blockIdx.x >> 4;
  const int nt = blockIdx.x & 15;
  if (mt >= mtTotal) return;
  const int e = ctrl[32 + mt];
  const int mbase = ctrl[32 + MAX_MT + mt];
  int mValid = ctrl[8 + e] + ctrl[e] - mbase;
  if (mValid > BM) mValid = BM;
  const int nbase = nt * BN;

  __shared__ __align__(16) short sA[3][BM * BK];
  __shared__ __align__(16) short sB[3][BM * BK];
  __shared__ int sTok[BM];
  __shared__ float sWgt[BM];

  const int tid = threadIdx.x;
  if (tid < BM) {
    const int p = mbase + (tid < mValid ? tid : 0);
    sTok[tid] = pairTok[p];
    sWgt[tid] = pairWgt[p];
  }
  __syncthreads();

  const int c0 = tid, c1 = tid + 256;
  const int r0 = c0 >> 2, r1 = c1 >> 2;
  const int kg0 = (c0 & 3) ^ ((r0 >> 1) & 3);
  const int kg1 = (c1 & 3) ^ ((r1 >> 1) & 3);

  size_t pa0 = (size_t)(mbase + r0); if (pa0 > MAXPAIR - 1) pa0 = MAXPAIR - 1;
  size_t pa1 = (size_t)(mbase + r1); if (pa1 > MAXPAIR - 1) pa1 = MAXPAIR - 1;
  const unsigned short* srcA0 = hbuf + pa0 * F_DIM + kg0 * 8;
  const unsigned short* srcA1 = hbuf + pa1 * F_DIM + kg1 * 8;
  const size_t wbase = (size_t)e * H_DIM * F_DIM;
  const float *fw0, *fw1;
  const unsigned short *pw0, *pw1;
  if constexpr (BBF) {
    pw0 = w2b + wbase + (size_t)(nbase + r0) * F_DIM + kg0 * 8;
    pw1 = w2b + wbase + (size_t)(nbase + r1) * F_DIM + kg1 * 8;
  } else {
    fw0 = w2f + wbase + (size_t)(nbase + r0) * F_DIM + kg0 * 8;
    fw1 = w2f + wbase + (size_t)(nbase + r1) * F_DIM + kg1 * 8;
  }

  f32x4 acc[4][4];
  const f32x4 fz = {0.f, 0.f, 0.f, 0.f};
#pragma unroll
  for (int i = 0; i < 4; ++i)
#pragma unroll
    for (int j = 0; j < 4; ++j) acc[i][j] = fz;

  const int lane = tid & 63, wid = tid >> 6;
  const int wm = (wid >> 1) * 64, wn = (wid & 1) * 64;
  const int rl = lane & 15, kq = lane >> 4;

  int aIdx[4], bIdx[4];
#pragma unroll
  for (int i = 0; i < 4; ++i) {
    const int ra = wm + i * 16 + rl;
    aIdx[i] = ra * BK + ((kq ^ ((ra >> 1) & 3)) * 8);
    const int rb = wn + i * 16 + rl;
    bIdx[i] = rb * BK + ((kq ^ ((rb >> 1) & 3)) * 8);
  }

#define STAGE2(buf, k0)                                                        \
  {                                                                            \
    GLD16(srcA0 + (k0), &sA[buf][c0 * 8]);                                     \
    GLD16(srcA1 + (k0), &sA[buf][c1 * 8]);                                     \
    if constexpr (BBF) {                                                       \
      GLD16(pw0 + (k0), &sB[buf][c0 * 8]);                                     \
      GLD16(pw1 + (k0), &sB[buf][c1 * 8]);                                     \
    } else {                                                                   \
      f32x4 t0 = *(const f32x4*)(fw0 + (k0));                                  \
      f32x4 t1 = *(const f32x4*)(fw0 + (k0) + 4);                              \
      *(s16x8*)&sB[buf][c0 * 8] = pack8(t0, t1);                               \
      t0 = *(const f32x4*)(fw1 + (k0));                                        \
      t1 = *(const f32x4*)(fw1 + (k0) + 4);                                    \
      *(s16x8*)&sB[buf][c1 * 8] = pack8(t0, t1);                               \
    }                                                                          \
  }

  STAGE2(0, 0);
  STAGE2(1, BK);

  const int NS = F_DIM / BK;  // 128
  int cur = 0;
  for (int s = 0; s < NS; ++s) {
    if (s + 2 < NS) {
      const int nxt = (cur + 2 >= 3) ? cur - 1 : cur + 2;
      STAGE2(nxt, (s + 2) * BK);
      if constexpr (BBF)
        asm volatile("s_waitcnt vmcnt(8)" ::: "memory");
      else
        asm volatile("s_waitcnt vmcnt(0) lgkmcnt(0)" ::: "memory");
    } else if (s + 2 == NS) {
      if constexpr (BBF)
        asm volatile("s_waitcnt vmcnt(4)" ::: "memory");
      else
        asm volatile("s_waitcnt vmcnt(0) lgkmcnt(0)" ::: "memory");
    } else {
      asm volatile("s_waitcnt vmcnt(0) lgkmcnt(0)" ::: "memory");
    }
    __builtin_amdgcn_s_barrier();
    asm volatile("" ::: "memory");

    bf16x8 af[4], bf[4];
#pragma unroll
    for (int i = 0; i < 4; ++i) {
      af[i] = *(const bf16x8*)&sA[cur][aIdx[i]];
      bf[i] = *(const bf16x8*)&sB[cur][bIdx[i]];
    }
    __builtin_amdgcn_s_setprio(1);
#pragma unroll
    for (int mr = 0; mr < 4; ++mr)
#pragma unroll
      for (int nr = 0; nr < 4; ++nr)
        acc[mr][nr] = __builtin_amdgcn_mfma_f32_16x16x32_bf16(
            af[mr], bf[nr], acc[mr][nr], 0, 0, 0);
    __builtin_amdgcn_s_setprio(0);
    asm volatile("" ::: "memory");
    __builtin_amdgcn_s_barrier();
    cur = (cur + 1 >= 3) ? 0 : cur + 1;
  }

#pragma unroll
  for (int mr = 0; mr < 4; ++mr) {
#pragma unroll
    for (int j = 0; j < 4; ++j) {
      const int row = wm + mr * 16 + kq * 4 + j;
      if (row < mValid) {
        const int tok = sTok[row];
        const float w = sWgt[row];
        float* dst = out + (size_t)tok * H_DIM + nbase + wn + rl;
#pragma unroll
        for (int nr = 0; nr < 4; ++nr)
          unsafeAtomicAdd(dst + nr * 16, w * acc[mr][nr][j]);
      }
    }
  }
#undef STAGE2
}

// ---------------------------------------------------------------------------
extern "C" void kernel_launch(void* const* d_in, const int* in_sizes, int n_in,
                              void* d_out, int out_size, void* d_ws,
                              size_t ws_size, hipStream_t stream) {
  const float* x  = (const float*)d_in[0];
  const float* gw = (const float*)d_in[1];
  const float* w1 = (const float*)d_in[2];
  const float* w3 = (const float*)d_in[3];
  const float* w2 = (const float*)d_in[4];
  float* out = (float*)d_out;                  // [T, H]
  float* logits = out + (size_t)T_TOK * H_DIM; // [T, E]

  char* ws = (char*)d_ws;
  const size_t HDR = 1u << 20;
  const size_t XB_SZ = (size_t)T_TOK * H_DIM * 2;           // 32 MiB
  const size_t HB_SZ = (size_t)MAXPAIR * F_DIM * 2;         // 128 MiB
  const size_t W_SZ  = (size_t)E_NUM * F_DIM * H_DIM * 2;   // 128 MiB each

  int* ctrl = (int*)(ws);
  int* tIdx = (int*)(ws + 4096);
  float* tW = (float*)(ws + 4096 + 65536);
  int* pairTok = (int*)(ws + 4096 + 131072);
  float* pairWgt = (float*)(ws + 4096 + 196608);
  unsigned short* xb = (unsigned short*)(ws + HDR);
  unsigned short* hbuf = (unsigned short*)(ws + HDR + XB_SZ);
  unsigned short* w1b = (unsigned short*)(ws + HDR + XB_SZ + HB_SZ);
  unsigned short* w3b = w1b + W_SZ / 2;
  unsigned short* w2b = w3b + W_SZ / 2;

  const bool cw13 = ws_size >= HDR + XB_SZ + HB_SZ + 2 * W_SZ;
  const bool cw2  = ws_size >= HDR + XB_SZ + HB_SZ + 3 * W_SZ;

  hipMemsetAsync(ctrl, 0, 4096, stream);
  hipMemsetAsync(out, 0, (size_t)T_TOK * H_DIM * sizeof(float), stream);

  // Router + fused w1/w3 converts (6144 blocks) — or plain router if no ws.
  if (cw13)
    router_conv_kernel<<<6144, 256, 0, stream>>>(
        x, gw, logits, xb, ctrl, tIdx, tW, w1, w1b, w3, w3b, NCONV13);
  else
    router_conv_kernel<<<T_TOK / 4, 256, 0, stream>>>(
        x, gw, logits, xb, ctrl, tIdx, tW, w1, w1b, w3, w3b, 0);

  plan_kernel<<<1, 256, 0, stream>>>(ctrl);
  scatter_kernel<<<T_TOK / 256, 256, 0, stream>>>(tIdx, tW, ctrl, pairTok, pairWgt);

  const int NG = MAX_MT * 32;  // 4352 gemm blocks
  if (cw13) {
    const int nconv = cw2 ? NCONV : 0;
    gemm1_kernel<1><<<NG + nconv, 256, 0, stream>>>(
        w1, w3, w1b, w3b, xb, ctrl, pairTok, hbuf, w2, w2b, nconv);
  } else {
    gemm1_kernel<0><<<NG, 256, 0, stream>>>(
        w1, w3, w1b, w3b, xb, ctrl, pairTok, hbuf, w2, w2b, 0);
  }
  if (cw2)
    gemm2_kernel<1><<<MAX_MT * 16, 256, 0, stream>>>(w2, w2b, hbuf, ctrl,
                                                     pairTok, pairWgt, out);
  else
    gemm2_kernel<0><<<MAX_MT * 16, 256, 0, stream>>>(w2, w2b, hbuf, ctrl,
                                                     pairTok, pairWgt, out);
}

// Round 10
// 1434.805 us; speedup vs baseline: 3.5428x; 1.0055x over previous
//
#include <hip/hip_runtime.h>
#include <math.h>

#define T_TOK 8192
#define H_DIM 2048
#define F_DIM 4096
#define E_NUM 8
#define MAXPAIR (T_TOK * 2)
#define MAX_MT 136
#define BM 128
#define BN 128
#define BK 32
#define NCONV 2048   // w2-convert blocks fused into gemm1 dispatch
#define NCONV13 4096 // w1/w3-convert blocks fused into router dispatch

typedef __attribute__((ext_vector_type(4))) float f32x4;
typedef __attribute__((ext_vector_type(8))) short s16x8;
typedef __attribute__((ext_vector_type(8))) __bf16 bf16x8;
typedef __attribute__((ext_vector_type(4))) unsigned short u16x4;

__device__ __forceinline__ unsigned short f2bf(float f) {
  unsigned int u = __float_as_uint(f);
  u += 0x7FFFu + ((u >> 16) & 1u);
  return (unsigned short)(u >> 16);
}

__device__ __forceinline__ s16x8 pack8(f32x4 a, f32x4 b) {
  s16x8 r;
  r[0] = (short)f2bf(a.x); r[1] = (short)f2bf(a.y);
  r[2] = (short)f2bf(a.z); r[3] = (short)f2bf(a.w);
  r[4] = (short)f2bf(b.x); r[5] = (short)f2bf(b.y);
  r[6] = (short)f2bf(b.z); r[7] = (short)f2bf(b.w);
  return r;
}

#define GLD16(gsrc, ldst)                                                      \
  __builtin_amdgcn_global_load_lds(                                            \
      (__attribute__((address_space(1))) void*)(gsrc),                         \
      (__attribute__((address_space(3))) void*)(ldst), 16, 0, 0)

// ---------------------------------------------------------------------------
// Router + fused w1/w3 fp32->bf16 converts (verified round 9)
// ---------------------------------------------------------------------------
__global__ __launch_bounds__(256) void router_conv_kernel(
    const float* __restrict__ x, const float* __restrict__ gw,
    float* __restrict__ logits, unsigned short* __restrict__ xb,
    int* __restrict__ ctrl, int* __restrict__ tIdx, float* __restrict__ tW,
    const float* __restrict__ w1f, unsigned short* __restrict__ w1b,
    const float* __restrict__ w3f, unsigned short* __restrict__ w3b,
    int nconv) {
  int rb = blockIdx.x;  // router block id
  if (nconv) {
    const int bid = blockIdx.x;
    if ((bid % 3) != 2) {
      const int cid = bid - (bid + 1) / 3;           // 0..4095
      const float* src = (cid < 2048) ? w1f : w3f;
      unsigned short* dst = (cid < 2048) ? w1b : w3b;
      const long long base = (long long)(cid & 2047) * 4096;
#pragma unroll
      for (int it = 0; it < 16; ++it) {
        const long long i = base + it * 256 + threadIdx.x;
        f32x4 a = *(const f32x4*)(src + i * 8);
        f32x4 b = *(const f32x4*)(src + i * 8 + 4);
        *(s16x8*)(dst + i * 8) = pack8(a, b);
      }
      return;
    }
    rb = bid / 3;  // 0..2047
  }

  const int wid = threadIdx.x >> 6, lane = threadIdx.x & 63;
  const int t = rb * 4 + wid;
  const float* xr = x + (size_t)t * H_DIM;
  float acc[E_NUM];
#pragma unroll
  for (int e = 0; e < E_NUM; ++e) acc[e] = 0.f;
#pragma unroll
  for (int c = 0; c < H_DIM / 256; ++c) {
    const int h0 = c * 256 + lane * 4;
    f32x4 xv = *(const f32x4*)(xr + h0);
    u16x4 p;
    p.x = f2bf(xv.x); p.y = f2bf(xv.y); p.z = f2bf(xv.z); p.w = f2bf(xv.w);
    *(u16x4*)(xb + (size_t)t * H_DIM + h0) = p;
#pragma unroll
    for (int e = 0; e < E_NUM; ++e) {
      f32x4 gv = *(const f32x4*)(gw + (size_t)e * H_DIM + h0);
      acc[e] += xv.x * gv.x + xv.y * gv.y + xv.z * gv.z + xv.w * gv.w;
    }
  }
#pragma unroll
  for (int e = 0; e < E_NUM; ++e) {
#pragma unroll
    for (int off = 32; off >= 1; off >>= 1) acc[e] += __shfl_xor(acc[e], off, 64);
  }
  if (lane == 0) {
#pragma unroll
    for (int e = 0; e < E_NUM; ++e) logits[(size_t)t * E_NUM + e] = acc[e];
    int i0 = 0;
    float m0 = acc[0];
    for (int e = 1; e < E_NUM; ++e)
      if (acc[e] > m0) { m0 = acc[e]; i0 = e; }
    int i1 = -1;
    float m1 = -3.4e38f;
    for (int e = 0; e < E_NUM; ++e)
      if (e != i0 && acc[e] > m1) { m1 = acc[e]; i1 = e; }
    float ex = expf(m1 - m0);
    float w0 = 1.f / (1.f + ex);
    float w1 = ex * w0;
    tIdx[t * 2] = i0; tIdx[t * 2 + 1] = i1;
    tW[t * 2] = w0;  tW[t * 2 + 1] = w1;
    atomicAdd(&ctrl[i0], 1);
    atomicAdd(&ctrl[i1], 1);
  }
}

// ---------------------------------------------------------------------------
// Plan (parallel): offsets, cursors, flat M-tile map
// ---------------------------------------------------------------------------
__global__ __launch_bounds__(256) void plan_kernel(int* __restrict__ ctrl) {
  __shared__ int cnt[E_NUM], offs[E_NUM + 1], tbase[E_NUM + 1];
  const int t = threadIdx.x;
  if (t < E_NUM) cnt[t] = ctrl[t];
  __syncthreads();
  if (t == 0) {
    int off = 0, mt = 0;
    for (int e = 0; e < E_NUM; ++e) {
      offs[e] = off; tbase[e] = mt;
      ctrl[8 + e] = off;
      ctrl[16 + e] = off;
      off += cnt[e];
      mt += (cnt[e] + BM - 1) / BM;
    }
    offs[E_NUM] = off; tbase[E_NUM] = mt;
    ctrl[24] = mt;
  }
  __syncthreads();
  const int total = tbase[E_NUM];
  for (int i = t; i < total; i += 256) {
    int e = 0;
    while (tbase[e + 1] <= i) ++e;
    ctrl[32 + i] = e;
    ctrl[32 + MAX_MT + i] = offs[e] + (i - tbase[e]) * BM;
  }
}

__global__ __launch_bounds__(256) void scatter_kernel(
    const int* __restrict__ tIdx, const float* __restrict__ tW,
    int* __restrict__ ctrl, int* __restrict__ pairTok,
    float* __restrict__ pairWgt) {
  const int t = blockIdx.x * 256 + threadIdx.x;
  if (t >= T_TOK) return;
#pragma unroll
  for (int j = 0; j < 2; ++j) {
    const int e = tIdx[t * 2 + j];
    const int pos = atomicAdd(&ctrl[16 + e], 1);
    pairTok[pos] = t;
    pairWgt[pos] = tW[t * 2 + j];
  }
}

// ---------------------------------------------------------------------------
// GEMM1: h = silu(x·w1^T) * (x·w3^T)  (bf16 out)
// NEW SCHEDULE: 3 buffers, ONE barrier per K-step, wait-after-compute with
// counted vmcnt(6) (retires exactly the stage needed next step). Step order:
//   STAGE(s+2) -> ds_read+MFMA(buf s%3) -> vmcnt(6) -> s_barrier
// WAR safe: stage(s+3) overwrites buf[s%3], issued only after barrier(s),
// which waves pass only after their reads of buf[s%3] completed.
// w2-convert blocks fused 1-per-3 (verified round 5/9).
// ---------------------------------------------------------------------------
template <int BBF>
__global__ __launch_bounds__(256, 2) void gemm1_kernel(
    const float* __restrict__ w1f, const float* __restrict__ w3f,
    const unsigned short* __restrict__ w1b,
    const unsigned short* __restrict__ w3b,
    const unsigned short* __restrict__ xb, const int* __restrict__ ctrl,
    const int* __restrict__ pairTok, unsigned short* __restrict__ hbuf,
    const float* __restrict__ w2f, unsigned short* __restrict__ w2b,
    int nconv) {
  int gid = blockIdx.x;
  const int nconv3 = nconv * 3;
  if (gid < nconv3) {
    if ((gid % 3) == 2) {
      const int cid = gid / 3;
      const long long per = (long long)E_NUM * F_DIM * H_DIM / 8 / NCONV;
      long long i = (long long)cid * per + threadIdx.x;
      const long long end = (long long)(cid + 1) * per;
      for (; i < end; i += 256) {
        f32x4 a = *(const f32x4*)(w2f + i * 8);
        f32x4 b = *(const f32x4*)(w2f + i * 8 + 4);
        *(s16x8*)(w2b + i * 8) = pack8(a, b);
      }
      return;
    }
    gid = gid - (gid + 1) / 3;
  } else {
    gid = gid - nconv;
  }

  const int mtTotal = ctrl[24];
  const int mt = gid >> 5;   // nt-major: same-weight-tile blocks 32 apart
  const int nt = gid & 31;   // -> same XCD -> L2 reuse
  if (mt >= mtTotal) return;
  const int e = ctrl[32 + mt];
  const int mbase = ctrl[32 + MAX_MT + mt];
  int mValid = ctrl[8 + e] + ctrl[e] - mbase;
  if (mValid > BM) mValid = BM;
  const int nbase = nt * BN;

  __shared__ __align__(16) short sA[3][BM * BK];
  __shared__ __align__(16) short sB1[3][BM * BK];
  __shared__ __align__(16) short sB3[3][BM * BK];
  __shared__ int sTok[BM];

  const int tid = threadIdx.x;
  if (tid < BM) sTok[tid] = pairTok[mbase + (tid < mValid ? tid : 0)];
  __syncthreads();

  const int c0 = tid, c1 = tid + 256;
  const int r0 = c0 >> 2, r1 = c1 >> 2;
  const int kg0 = (c0 & 3) ^ ((r0 >> 1) & 3);
  const int kg1 = (c1 & 3) ^ ((r1 >> 1) & 3);

  const unsigned short* srcA0 = xb + (size_t)sTok[r0] * H_DIM + kg0 * 8;
  const unsigned short* srcA1 = xb + (size_t)sTok[r1] * H_DIM + kg1 * 8;
  const size_t wbase = (size_t)e * F_DIM * H_DIM;
  const float *f10, *f11, *f30, *f31;
  const unsigned short *p10, *p11, *p30, *p31;
  if constexpr (BBF) {
    p10 = w1b + wbase + (size_t)(nbase + r0) * H_DIM + kg0 * 8;
    p11 = w1b + wbase + (size_t)(nbase + r1) * H_DIM + kg1 * 8;
    p30 = w3b + wbase + (size_t)(nbase + r0) * H_DIM + kg0 * 8;
    p31 = w3b + wbase + (size_t)(nbase + r1) * H_DIM + kg1 * 8;
  } else {
    f10 = w1f + wbase + (size_t)(nbase + r0) * H_DIM + kg0 * 8;
    f11 = w1f + wbase + (size_t)(nbase + r1) * H_DIM + kg1 * 8;
    f30 = w3f + wbase + (size_t)(nbase + r0) * H_DIM + kg0 * 8;
    f31 = w3f + wbase + (size_t)(nbase + r1) * H_DIM + kg1 * 8;
  }

  f32x4 acc1[4][4], acc3[4][4];
  const f32x4 fz = {0.f, 0.f, 0.f, 0.f};
#pragma unroll
  for (int i = 0; i < 4; ++i)
#pragma unroll
    for (int j = 0; j < 4; ++j) { acc1[i][j] = fz; acc3[i][j] = fz; }

  const int lane = tid & 63, wid = tid >> 6;
  const int wm = (wid >> 1) * 64, wn = (wid & 1) * 64;
  const int rl = lane & 15, kq = lane >> 4;

  int aIdx[4], bIdx[4];
#pragma unroll
  for (int i = 0; i < 4; ++i) {
    const int ra = wm + i * 16 + rl;
    aIdx[i] = ra * BK + ((kq ^ ((ra >> 1) & 3)) * 8);
    const int rb = wn + i * 16 + rl;
    bIdx[i] = rb * BK + ((kq ^ ((rb >> 1) & 3)) * 8);
  }

#define STAGE1(buf, k0)                                                        \
  {                                                                            \
    GLD16(srcA0 + (k0), &sA[buf][c0 * 8]);                                     \
    GLD16(srcA1 + (k0), &sA[buf][c1 * 8]);                                     \
    if constexpr (BBF) {                                                       \
      GLD16(p10 + (k0), &sB1[buf][c0 * 8]);                                    \
      GLD16(p11 + (k0), &sB1[buf][c1 * 8]);                                    \
      GLD16(p30 + (k0), &sB3[buf][c0 * 8]);                                    \
      GLD16(p31 + (k0), &sB3[buf][c1 * 8]);                                    \
    } else {                                                                   \
      f32x4 t0 = *(const f32x4*)(f10 + (k0));                                  \
      f32x4 t1 = *(const f32x4*)(f10 + (k0) + 4);                              \
      *(s16x8*)&sB1[buf][c0 * 8] = pack8(t0, t1);                              \
      t0 = *(const f32x4*)(f11 + (k0));                                        \
      t1 = *(const f32x4*)(f11 + (k0) + 4);                                    \
      *(s16x8*)&sB1[buf][c1 * 8] = pack8(t0, t1);                              \
      t0 = *(const f32x4*)(f30 + (k0));                                        \
      t1 = *(const f32x4*)(f30 + (k0) + 4);                                    \
      *(s16x8*)&sB3[buf][c0 * 8] = pack8(t0, t1);                              \
      t0 = *(const f32x4*)(f31 + (k0));                                        \
      t1 = *(const f32x4*)(f31 + (k0) + 4);                                    \
      *(s16x8*)&sB3[buf][c1 * 8] = pack8(t0, t1);                              \
    }                                                                          \
  }

  // prologue: stage 0,1; retire stage 0; barrier
  STAGE1(0, 0);
  STAGE1(1, BK);
  if constexpr (BBF)
    asm volatile("s_waitcnt vmcnt(6)" ::: "memory");
  else
    asm volatile("s_waitcnt vmcnt(0) lgkmcnt(0)" ::: "memory");
  __builtin_amdgcn_s_barrier();
  asm volatile("" ::: "memory");

  const int NS = H_DIM / BK;  // 64
  int cur = 0;
  for (int s = 0; s < NS; ++s) {
    if (s + 2 < NS) {
      const int nxt = (cur + 2 >= 3) ? cur - 1 : cur + 2;
      STAGE1(nxt, (s + 2) * BK);
    }
    asm volatile("" ::: "memory");

    bf16x8 af[4], bf1[4], bf3[4];
#pragma unroll
    for (int i = 0; i < 4; ++i) {
      af[i] = *(const bf16x8*)&sA[cur][aIdx[i]];
      bf1[i] = *(const bf16x8*)&sB1[cur][bIdx[i]];
      bf3[i] = *(const bf16x8*)&sB3[cur][bIdx[i]];
    }
    __builtin_amdgcn_s_setprio(1);
#pragma unroll
    for (int mr = 0; mr < 4; ++mr)
#pragma unroll
      for (int nr = 0; nr < 4; ++nr) {
        acc1[mr][nr] = __builtin_amdgcn_mfma_f32_16x16x32_bf16(
            af[mr], bf1[nr], acc1[mr][nr], 0, 0, 0);
        acc3[mr][nr] = __builtin_amdgcn_mfma_f32_16x16x32_bf16(
            af[mr], bf3[nr], acc3[mr][nr], 0, 0, 0);
      }
    __builtin_amdgcn_s_setprio(0);
    asm volatile("" ::: "memory");

    if (s + 1 < NS) {
      // retire the stage needed by step s+1; never drain the newest stage
      if constexpr (BBF) {
        if (s + 2 < NS)
          asm volatile("s_waitcnt vmcnt(6)" ::: "memory");
        else
          asm volatile("s_waitcnt vmcnt(0)" ::: "memory");
      } else {
        asm volatile("s_waitcnt vmcnt(0) lgkmcnt(0)" ::: "memory");
      }
      __builtin_amdgcn_s_barrier();
      asm volatile("" ::: "memory");
    }
    cur = (cur + 1 >= 3) ? 0 : cur + 1;
  }

#pragma unroll
  for (int mr = 0; mr < 4; ++mr) {
#pragma unroll
    for (int j = 0; j < 4; ++j) {
      const int row = wm + mr * 16 + kq * 4 + j;
      if (row < mValid) {
        unsigned short* dst =
            hbuf + (size_t)(mbase + row) * F_DIM + nbase + wn + rl;
#pragma unroll
        for (int nr = 0; nr < 4; ++nr) {
          const float z = acc1[mr][nr][j];
          const float hv = (z / (1.f + expf(-z))) * acc3[mr][nr][j];
          dst[nr * 16] = f2bf(hv);
        }
      }
    }
  }
#undef STAGE1
}

// ---------------------------------------------------------------------------
// GEMM2: out[tok] += wgt * (h·w2^T)  — same 1-barrier counted schedule
// (4 loads/stage -> steady vmcnt(4))
// ---------------------------------------------------------------------------
template <int BBF>
__global__ __launch_bounds__(256, 2) void gemm2_kernel(
    const float* __restrict__ w2f, const unsigned short* __restrict__ w2b,
    const unsigned short* __restrict__ hbuf, const int* __restrict__ ctrl,
    const int* __restrict__ pairTok, const float* __restrict__ pairWgt,
    float* __restrict__ out) {
  const int mtTotal = ctrl[24];
  const int mt = blockIdx.x >> 4;
  const int nt = blockIdx.x & 15;
  if (mt >= mtTotal) return;
  const int e = ctrl[32 + mt];
  const int mbase = ctrl[32 + MAX_MT + mt];
  int mValid = ctrl[8 + e] + ctrl[e] - mbase;
  if (mValid > BM) mValid = BM;
  const int nbase = nt * BN;

  __shared__ __align__(16) short sA[3][BM * BK];
  __shared__ __align__(16) short sB[3][BM * BK];
  __shared__ int sTok[BM];
  __shared__ float sWgt[BM];

  const int tid = threadIdx.x;
  if (tid < BM) {
    const int p = mbase + (tid < mValid ? tid : 0);
    sTok[tid] = pairTok[p];
    sWgt[tid] = pairWgt[p];
  }
  __syncthreads();

  const int c0 = tid, c1 = tid + 256;
  const int r0 = c0 >> 2, r1 = c1 >> 2;
  const int kg0 = (c0 & 3) ^ ((r0 >> 1) & 3);
  const int kg1 = (c1 & 3) ^ ((r1 >> 1) & 3);

  size_t pa0 = (size_t)(mbase + r0); if (pa0 > MAXPAIR - 1) pa0 = MAXPAIR - 1;
  size_t pa1 = (size_t)(mbase + r1); if (pa1 > MAXPAIR - 1) pa1 = MAXPAIR - 1;
  const unsigned short* srcA0 = hbuf + pa0 * F_DIM + kg0 * 8;
  const unsigned short* srcA1 = hbuf + pa1 * F_DIM + kg1 * 8;
  const size_t wbase = (size_t)e * H_DIM * F_DIM;
  const float *fw0, *fw1;
  const unsigned short *pw0, *pw1;
  if constexpr (BBF) {
    pw0 = w2b + wbase + (size_t)(nbase + r0) * F_DIM + kg0 * 8;
    pw1 = w2b + wbase + (size_t)(nbase + r1) * F_DIM + kg1 * 8;
  } else {
    fw0 = w2f + wbase + (size_t)(nbase + r0) * F_DIM + kg0 * 8;
    fw1 = w2f + wbase + (size_t)(nbase + r1) * F_DIM + kg1 * 8;
  }

  f32x4 acc[4][4];
  const f32x4 fz = {0.f, 0.f, 0.f, 0.f};
#pragma unroll
  for (int i = 0; i < 4; ++i)
#pragma unroll
    for (int j = 0; j < 4; ++j) acc[i][j] = fz;

  const int lane = tid & 63, wid = tid >> 6;
  const int wm = (wid >> 1) * 64, wn = (wid & 1) * 64;
  const int rl = lane & 15, kq = lane >> 4;

  int aIdx[4], bIdx[4];
#pragma unroll
  for (int i = 0; i < 4; ++i) {
    const int ra = wm + i * 16 + rl;
    aIdx[i] = ra * BK + ((kq ^ ((ra >> 1) & 3)) * 8);
    const int rb = wn + i * 16 + rl;
    bIdx[i] = rb * BK + ((kq ^ ((rb >> 1) & 3)) * 8);
  }

#define STAGE2(buf, k0)                                                        \
  {                                                                            \
    GLD16(srcA0 + (k0), &sA[buf][c0 * 8]);                                     \
    GLD16(srcA1 + (k0), &sA[buf][c1 * 8]);                                     \
    if constexpr (BBF) {                                                       \
      GLD16(pw0 + (k0), &sB[buf][c0 * 8]);                                     \
      GLD16(pw1 + (k0), &sB[buf][c1 * 8]);                                     \
    } else {                                                                   \
      f32x4 t0 = *(const f32x4*)(fw0 + (k0));                                  \
      f32x4 t1 = *(const f32x4*)(fw0 + (k0) + 4);                              \
      *(s16x8*)&sB[buf][c0 * 8] = pack8(t0, t1);                               \
      t0 = *(const f32x4*)(fw1 + (k0));                                        \
      t1 = *(const f32x4*)(fw1 + (k0) + 4);                                    \
      *(s16x8*)&sB[buf][c1 * 8] = pack8(t0, t1);                               \
    }                                                                          \
  }

  STAGE2(0, 0);
  STAGE2(1, BK);
  if constexpr (BBF)
    asm volatile("s_waitcnt vmcnt(4)" ::: "memory");
  else
    asm volatile("s_waitcnt vmcnt(0) lgkmcnt(0)" ::: "memory");
  __builtin_amdgcn_s_barrier();
  asm volatile("" ::: "memory");

  const int NS = F_DIM / BK;  // 128
  int cur = 0;
  for (int s = 0; s < NS; ++s) {
    if (s + 2 < NS) {
      const int nxt = (cur + 2 >= 3) ? cur - 1 : cur + 2;
      STAGE2(nxt, (s + 2) * BK);
    }
    asm volatile("" ::: "memory");

    bf16x8 af[4], bf[4];
#pragma unroll
    for (int i = 0; i < 4; ++i) {
      af[i] = *(const bf16x8*)&sA[cur][aIdx[i]];
      bf[i] = *(const bf16x8*)&sB[cur][bIdx[i]];
    }
    __builtin_amdgcn_s_setprio(1);
#pragma unroll
    for (int mr = 0; mr < 4; ++mr)
#pragma unroll
      for (int nr = 0; nr < 4; ++nr)
        acc[mr][nr] = __builtin_amdgcn_mfma_f32_16x16x32_bf16(
            af[mr], bf[nr], acc[mr][nr], 0, 0, 0);
    __builtin_amdgcn_s_setprio(0);
    asm volatile("" ::: "memory");

    if (s + 1 < NS) {
      if constexpr (BBF) {
        if (s + 2 < NS)
          asm volatile("s_waitcnt vmcnt(4)" ::: "memory");
        else
          asm volatile("s_waitcnt vmcnt(0)" ::: "memory");
      } else {
        asm volatile("s_waitcnt vmcnt(0) lgkmcnt(0)" ::: "memory");
      }
      __builtin_amdgcn_s_barrier();
      asm volatile("" ::: "memory");
    }
    cur = (cur + 1 >= 3) ? 0 : cur + 1;
  }

#pragma unroll
  for (int mr = 0; mr < 4; ++mr) {
#pragma unroll
    for (int j = 0; j < 4; ++j) {
      const int row = wm + mr * 16 + kq * 4 + j;
      if (row < mValid) {
        const int tok = sTok[row];
        const float w = sWgt[row];
        float* dst = out + (size_t)tok * H_DIM + nbase + wn + rl;
#pragma unroll
        for (int nr = 0; nr < 4; ++nr)
          unsafeAtomicAdd(dst + nr * 16, w * acc[mr][nr][j]);
      }
    }
  }
#undef STAGE2
}

// ---------------------------------------------------------------------------
extern "C" void kernel_launch(void* const* d_in, const int* in_sizes, int n_in,
                              void* d_out, int out_size, void* d_ws,
                              size_t ws_size, hipStream_t stream) {
  const float* x  = (const float*)d_in[0];
  const float* gw = (const float*)d_in[1];
  const float* w1 = (const float*)d_in[2];
  const float* w3 = (const float*)d_in[3];
  const float* w2 = (const float*)d_in[4];
  float* out = (float*)d_out;                  // [T, H]
  float* logits = out + (size_t)T_TOK * H_DIM; // [T, E]

  char* ws = (char*)d_ws;
  const size_t HDR = 1u << 20;
  const size_t XB_SZ = (size_t)T_TOK * H_DIM * 2;           // 32 MiB
  const size_t HB_SZ = (size_t)MAXPAIR * F_DIM * 2;         // 128 MiB
  const size_t W_SZ  = (size_t)E_NUM * F_DIM * H_DIM * 2;   // 128 MiB each

  int* ctrl = (int*)(ws);
  int* tIdx = (int*)(ws + 4096);
  float* tW = (float*)(ws + 4096 + 65536);
  int* pairTok = (int*)(ws + 4096 + 131072);
  float* pairWgt = (float*)(ws + 4096 + 196608);
  unsigned short* xb = (unsigned short*)(ws + HDR);
  unsigned short* hbuf = (unsigned short*)(ws + HDR + XB_SZ);
  unsigned short* w1b = (unsigned short*)(ws + HDR + XB_SZ + HB_SZ);
  unsigned short* w3b = w1b + W_SZ / 2;
  unsigned short* w2b = w3b + W_SZ / 2;

  const bool cw13 = ws_size >= HDR + XB_SZ + HB_SZ + 2 * W_SZ;
  const bool cw2  = ws_size >= HDR + XB_SZ + HB_SZ + 3 * W_SZ;

  hipMemsetAsync(ctrl, 0, 4096, stream);
  hipMemsetAsync(out, 0, (size_t)T_TOK * H_DIM * sizeof(float), stream);

  // Router + fused w1/w3 converts (6144 blocks) — or plain router if no ws.
  if (cw13)
    router_conv_kernel<<<6144, 256, 0, stream>>>(
        x, gw, logits, xb, ctrl, tIdx, tW, w1, w1b, w3, w3b, NCONV13);
  else
    router_conv_kernel<<<T_TOK / 4, 256, 0, stream>>>(
        x, gw, logits, xb, ctrl, tIdx, tW, w1, w1b, w3, w3b, 0);

  plan_kernel<<<1, 256, 0, stream>>>(ctrl);
  scatter_kernel<<<T_TOK / 256, 256, 0, stream>>>(tIdx, tW, ctrl, pairTok, pairWgt);

  const int NG = MAX_MT * 32;  // 4352 gemm blocks
  if (cw13) {
    const int nconv = cw2 ? NCONV : 0;
    gemm1_kernel<1><<<NG + nconv, 256, 0, stream>>>(
        w1, w3, w1b, w3b, xb, ctrl, pairTok, hbuf, w2, w2b, nconv);
  } else {
    gemm1_kernel<0><<<NG, 256, 0, stream>>>(
        w1, w3, w1b, w3b, xb, ctrl, pairTok, hbuf, w2, w2b, 0);
  }
  if (cw2)
    gemm2_kernel<1><<<MAX_MT * 16, 256, 0, stream>>>(w2, w2b, hbuf, ctrl,
                                                     pairTok, pairWgt, out);
  else
    gemm2_kernel<0><<<MAX_MT * 16, 256, 0, stream>>>(w2, w2b, hbuf, ctrl,
                                                     pairTok, pairWgt, out);
}